// Round 15
// baseline (15000.746 us; speedup 1.0000x reference)
//
#include <hip/hip_runtime.h>
#include <math.h>

#define TT 1024
#define CH 16
#define SMC 10
#define NCLS 10
#define JIT 1e-4f

__device__ __forceinline__ void tri_map(int tau, int& ti, int& tj) {
    int i = 0, r = tau;
    while (r >= i + 1) { r -= i + 1; i++; }
    ti = i; tj = r;
}

// ---------------- Btask = W W^T + diag(softplus(v)) ----------------
__global__ __launch_bounds__(256) void k_btask(const float* __restrict__ W,
                                               const float* __restrict__ v,
                                               float* __restrict__ Bt) {
    int t = threadIdx.x;
    for (int e = t; e < 17 * 17; e += 256) {
        int i = e / 17, j = e % 17;
        float s = 0.f;
        for (int r = 0; r < 3; r++) s += W[i * 3 + r] * W[j * 3 + r];
        if (i == j) s += log1pf(expf(v[i]));
        Bt[e] = s;
    }
}

// ---------------- Kxx build (lower 128-blocks) ----------------
__global__ __launch_bounds__(256) void k_build_kxx(const float* __restrict__ x,
                                                   const int* __restrict__ itr,
                                                   const float* __restrict__ lsp,
                                                   const float* __restrict__ noisep,
                                                   const float* __restrict__ Bt,
                                                   float* __restrict__ A, int b0) {
    int bi = blockIdx.x, bj = blockIdx.y, bz = blockIdx.z;
    if (bj > bi) return;
    int b = b0 + bz;
    __shared__ float sxi[128], sxj[128], Btl[289];
    __shared__ int sii[128], sij[128];
    int t = threadIdx.x;
    if (t < 128) { sxi[t] = x[b * TT + bi * 128 + t]; sii[t] = itr[b * TT + bi * 128 + t]; }
    else { int u = t - 128; sxj[u] = x[b * TT + bj * 128 + u]; sij[u] = itr[b * TT + bj * 128 + u]; }
    for (int e = t; e < 289; e += 256) Btl[e] = Bt[e];
    __syncthreads();
    float invls = 1.0f / lsp[0];
    float n2 = noisep[0] * noisep[0] + JIT;
    float* Ab = A + (size_t)bz * TT * TT;
    for (int l = 0; l < 64; l++) {
        int e = l * 256 + t;
        int r = e >> 7, c = e & 127;
        float d = (sxi[r] - sxj[c]) * invls;
        float kv = expf(-0.5f * d * d) * Btl[sii[r] * 17 + sij[c]];
        int gi = bi * 128 + r, gj = bj * 128 + c;
        if (gi == gj) kv += n2;
        Ab[(size_t)gi * TT + gj] = kv;
    }
}

// ---------------- G = Ksx^T build ([train j][test i]) ----------------
__global__ __launch_bounds__(256) void k_build_g(const float* __restrict__ xs,
                                                 const float* __restrict__ x,
                                                 const int* __restrict__ ite,
                                                 const int* __restrict__ itr,
                                                 const float* __restrict__ lsp,
                                                 const float* __restrict__ Bt,
                                                 float* __restrict__ G, int b0) {
    int bj = blockIdx.x, bi = blockIdx.y, bz = blockIdx.z;
    int b = b0 + bz;
    __shared__ float sxr[128], sxc[128], Btl[289];
    __shared__ int sir[128], sic[128];
    int t = threadIdx.x;
    if (t < 128) { sxr[t] = x[b * TT + bj * 128 + t]; sir[t] = itr[b * TT + bj * 128 + t]; }
    else { int u = t - 128; sxc[u] = xs[b * TT + bi * 128 + u]; sic[u] = ite[b * TT + bi * 128 + u]; }
    for (int e = t; e < 289; e += 256) Btl[e] = Bt[e];
    __syncthreads();
    float invls = 1.0f / lsp[0];
    float* Gb = G + (size_t)bz * TT * TT;
    for (int l = 0; l < 64; l++) {
        int e = l * 256 + t;
        int r = e >> 7, c = e & 127;
        float d = (sxc[c] - sxr[r]) * invls;
        float kv = expf(-0.5f * d * d) * Btl[sic[c] * 17 + sir[r]];
        Gb[(size_t)(bj * 128 + r) * TT + bi * 128 + c] = kv;
    }
}

// ---------------- z init: z = y - c ----------------
__global__ __launch_bounds__(256) void k_zinit(const float* __restrict__ values,
                                               const float* __restrict__ mc,
                                               float* __restrict__ zb, int b0) {
    int bz = blockIdx.x, t = threadIdx.x;
    float c0 = mc[0];
    for (int i = t; i < TT; i += 256) zb[bz * TT + i] = values[(size_t)(b0 + bz) * TT + i] - c0;
}

// ---------------- phase A, NB=128, internally 64-blocked factor ----------------
// Every block factors the 128x128 diag in LDS from UNMODIFIED A via
// {factor64(L00), rowTRSM(L10), parallel SYRK(D11), factor64(L11)}.
// bx==0: write factored diag -> Dfac. bx in [1,m]: A-panel solve (128 rows).
// withG: bx in [m+1,m+8]: G col-tile solve (128 cols; c==0 carries z as col 128).
__global__ __launch_bounds__(256) void k_A128(float* __restrict__ A,
                                              float* __restrict__ G,
                                              float* __restrict__ zb,
                                              float* __restrict__ Dfac,
                                              int k, int m, int withG) {
    int bx = blockIdx.x, bz = blockIdx.y;
    float* Ab = A + (size_t)bz * TT * TT;
    float* Gb = G + (size_t)bz * TT * TT;
    int kb = k * 128;
    __shared__ float Ld[128][129];
    __shared__ float WK[128][130];
    __shared__ float invl[128];
    int t = threadIdx.x;
    // load diag block (float4)
    for (int l = 0; l < 16; l++) {
        int e = l * 256 + t; int r = e >> 5, c4 = (e & 31) * 4;
        float4 v = *reinterpret_cast<const float4*>(&Ab[(size_t)(kb + r) * TT + kb + c4]);
        Ld[r][c4 + 0] = v.x; Ld[r][c4 + 1] = v.y; Ld[r][c4 + 2] = v.z; Ld[r][c4 + 3] = v.w;
    }
    int jtype = 0, r0 = 0, c0 = 0;
    if (bx >= 1 && bx <= m) {
        jtype = 1; r0 = kb + 128 * bx;
        for (int l = 0; l < 16; l++) {
            int e = l * 256 + t; int r = e >> 5, c4 = (e & 31) * 4;
            float4 v = *reinterpret_cast<const float4*>(&Ab[(size_t)(r0 + r) * TT + kb + c4]);
            WK[r][c4 + 0] = v.x; WK[r][c4 + 1] = v.y; WK[r][c4 + 2] = v.z; WK[r][c4 + 3] = v.w;
        }
    } else if (withG && bx > m) {
        jtype = 2; c0 = (bx - m - 1) * 128;
        for (int l = 0; l < 16; l++) {
            int e = l * 256 + t; int r = e >> 5, c4 = (e & 31) * 4;
            float4 v = *reinterpret_cast<const float4*>(&Gb[(size_t)(kb + r) * TT + c0 + c4]);
            WK[r][c4 + 0] = v.x; WK[r][c4 + 1] = v.y; WK[r][c4 + 2] = v.z; WK[r][c4 + 3] = v.w;
        }
        if (c0 == 0 && t < 128) WK[t][128] = zb[bz * TT + kb + t];
    }
    __syncthreads();
    // (a) factor64 on rows/cols 0..63
    for (int j = 0; j < 64; j++) {
        if (t == j) { float d = sqrtf(Ld[j][j]); Ld[j][j] = d; invl[j] = 1.0f / d; }
        __syncthreads();
        float lij = 0.f;
        if (t < 64 && t > j) { lij = Ld[t][j] * invl[j]; Ld[t][j] = lij; }
        __syncthreads();
        if (t < 64 && t > j) {
#pragma unroll 4
            for (int p = j + 1; p <= t; p++) Ld[t][p] -= lij * Ld[p][j];
        }
    }
    __syncthreads();
    // (b) L10 = D10 * L00^{-T}: thread t<64 owns row 64+t
    if (t < 64) {
        int rr = 64 + t;
        for (int j = 0; j < 64; j++) {
            float xv = Ld[rr][j] * invl[j];
            Ld[rr][j] = xv;
#pragma unroll 4
            for (int p = j + 1; p < 64; p++) Ld[rr][p] -= Ld[p][j] * xv;
        }
    }
    __syncthreads();
    // (c) D11 -= L10 L10^T (parallel, 256 threads, 4x4 acc)
    {
        int tx = t & 15, ty = t >> 4;
        float acc[4][4] = {};
        for (int p = 0; p < 64; p++) {
            float a0 = Ld[64 + ty * 4 + 0][p], a1 = Ld[64 + ty * 4 + 1][p];
            float a2 = Ld[64 + ty * 4 + 2][p], a3 = Ld[64 + ty * 4 + 3][p];
            float b0 = Ld[64 + tx * 4 + 0][p], b1 = Ld[64 + tx * 4 + 1][p];
            float b2 = Ld[64 + tx * 4 + 2][p], b3 = Ld[64 + tx * 4 + 3][p];
            acc[0][0] += a0 * b0; acc[0][1] += a0 * b1; acc[0][2] += a0 * b2; acc[0][3] += a0 * b3;
            acc[1][0] += a1 * b0; acc[1][1] += a1 * b1; acc[1][2] += a1 * b2; acc[1][3] += a1 * b3;
            acc[2][0] += a2 * b0; acc[2][1] += a2 * b1; acc[2][2] += a2 * b2; acc[2][3] += a2 * b3;
            acc[3][0] += a3 * b0; acc[3][1] += a3 * b1; acc[3][2] += a3 * b2; acc[3][3] += a3 * b3;
        }
        // reads cols <64, writes cols >=64 -> no intra-phase race
        for (int i = 0; i < 4; i++)
            for (int j = 0; j < 4; j++)
                Ld[64 + ty * 4 + i][64 + tx * 4 + j] -= acc[i][j];
    }
    __syncthreads();
    // (d) factor64 on rows/cols 64..127
    for (int j = 0; j < 64; j++) {
        int jj = 64 + j;
        if (t == j) { float d = sqrtf(Ld[jj][jj]); Ld[jj][jj] = d; invl[jj] = 1.0f / d; }
        __syncthreads();
        float lij = 0.f;
        if (t < 64 && t > j) { int rr = 64 + t; lij = Ld[rr][jj] * invl[jj]; Ld[rr][jj] = lij; }
        __syncthreads();
        if (t < 64 && t > j) {
            int rr = 64 + t;
#pragma unroll 4
            for (int p = j + 1; p <= t; p++) Ld[rr][64 + p] -= lij * Ld[64 + p][jj];
        }
    }
    __syncthreads();
    if (jtype == 0) {
        if (bx == 0) {
            float* Df = Dfac + ((size_t)bz * 8 + k) * 16384;
            for (int l = 0; l < 64; l++) {
                int e = l * 256 + t; int r = e >> 7, c = e & 127;
                Df[r * 128 + c] = Ld[r][c];
            }
        }
        return;
    }
    if (jtype == 1) {
        // panel solve X = B * Ldiag^{-T}: row-owner, single 128-deep pass
        if (t < 128) {
            for (int j = 0; j < 128; j++) {
                float xv = WK[t][j] * invl[j];
                WK[t][j] = xv;
#pragma unroll 4
                for (int p = j + 1; p < 128; p++) WK[t][p] -= Ld[p][j] * xv;
            }
        }
        __syncthreads();
        for (int l = 0; l < 16; l++) {
            int e = l * 256 + t; int r = e >> 5, c4 = (e & 31) * 4;
            float4 v = make_float4(WK[r][c4], WK[r][c4 + 1], WK[r][c4 + 2], WK[r][c4 + 3]);
            *reinterpret_cast<float4*>(&Ab[(size_t)(r0 + r) * TT + kb + c4]) = v;
        }
    } else {
        // G col-tile solve Y = Ldiag^{-1} Gt: col-owner, col 128 = z (c0==0)
        int ncol = 128 + ((c0 == 0) ? 1 : 0);
        if (t < ncol) {
            for (int j = 0; j < 128; j++) {
                float yv = WK[j][t] * invl[j];
                WK[j][t] = yv;
#pragma unroll 4
                for (int p = j + 1; p < 128; p++) WK[p][t] -= Ld[p][j] * yv;
            }
        }
        __syncthreads();
        for (int l = 0; l < 16; l++) {
            int e = l * 256 + t; int r = e >> 5, c4 = (e & 31) * 4;
            float4 v = make_float4(WK[r][c4], WK[r][c4 + 1], WK[r][c4 + 2], WK[r][c4 + 3]);
            *reinterpret_cast<float4*>(&Gb[(size_t)(kb + r) * TT + c0 + c4]) = v;
        }
        if (c0 == 0 && t < 128) zb[bz * TT + kb + t] = WK[t][128];
    }
}

// ---------------- phase B, NB=128, merged SYRK + G-update + z-update, XCD-pinned ----------------
__global__ __launch_bounds__(256) void k_B128(float* __restrict__ A,
                                              float* __restrict__ G,
                                              float* __restrict__ zb,
                                              int k, int m, int bc, int withG) {
    int lin = blockIdx.x;
    int slot = lin & 7, q = lin >> 3;
    int beta = ((slot - 4 * (q & 1)) & 7) + (blockIdx.y << 3);
    if (beta >= bc) return;
    float* Ab = A + (size_t)beta * TT * TT;
    float* Gb = G + (size_t)beta * TT * TT;
    int kb = k * 128;
    int TL = m * (m + 1) / 2;
    __shared__ __align__(16) float At[32][132];
    __shared__ __align__(16) float Bs[32][132];
    __shared__ float zk[128];
    int t = threadIdx.x, tx = t & 15, ty = t >> 4;
    if (q < TL) {
        // ---- SYRK 128x128 tile, K=128 ----
        int ti, tj; tri_map(q, ti, tj);
        int base = kb + 128;
        int r0 = base + ti * 128, c0 = base + tj * 128;
        float acc[8][8] = {};
        for (int s = 0; s < 4; s++) {
            int k0 = kb + s * 32;
            __syncthreads();
            for (int l = 0; l < 4; l++) {
                int f = l * 256 + t;
                int r = f >> 3, c4 = (f & 7) * 4;
                float4 va = *reinterpret_cast<const float4*>(&Ab[(size_t)(r0 + r) * TT + k0 + c4]);
                float4 vb = *reinterpret_cast<const float4*>(&Ab[(size_t)(c0 + r) * TT + k0 + c4]);
                At[c4 + 0][r] = va.x; At[c4 + 1][r] = va.y; At[c4 + 2][r] = va.z; At[c4 + 3][r] = va.w;
                Bs[c4 + 0][r] = vb.x; Bs[c4 + 1][r] = vb.y; Bs[c4 + 2][r] = vb.z; Bs[c4 + 3][r] = vb.w;
            }
            __syncthreads();
#pragma unroll 4
            for (int p = 0; p < 32; p++) {
                float4 a0 = *reinterpret_cast<const float4*>(&At[p][ty * 8]);
                float4 a1 = *reinterpret_cast<const float4*>(&At[p][ty * 8 + 4]);
                float4 b0 = *reinterpret_cast<const float4*>(&Bs[p][tx * 4]);
                float4 b1 = *reinterpret_cast<const float4*>(&Bs[p][tx * 4 + 64]);
                float aa[8] = {a0.x, a0.y, a0.z, a0.w, a1.x, a1.y, a1.z, a1.w};
                float bl[4] = {b0.x, b0.y, b0.z, b0.w};
                float bh[4] = {b1.x, b1.y, b1.z, b1.w};
                for (int i = 0; i < 8; i++) {
                    for (int j = 0; j < 4; j++) acc[i][j] += aa[i] * bl[j];
                    for (int j = 0; j < 4; j++) acc[i][j + 4] += aa[i] * bh[j];
                }
            }
        }
        for (int i = 0; i < 8; i++) {
            int rr = ty * 8 + i;
            float* cp0 = &Ab[(size_t)(r0 + rr) * TT + c0 + tx * 4];
            float4 cv0 = *reinterpret_cast<float4*>(cp0);
            cv0.x -= acc[i][0]; cv0.y -= acc[i][1]; cv0.z -= acc[i][2]; cv0.w -= acc[i][3];
            *reinterpret_cast<float4*>(cp0) = cv0;
            float* cp1 = cp0 + 64;
            float4 cv1 = *reinterpret_cast<float4*>(cp1);
            cv1.x -= acc[i][4]; cv1.y -= acc[i][5]; cv1.z -= acc[i][6]; cv1.w -= acc[i][7];
            *reinterpret_cast<float4*>(cp1) = cv1;
        }
        return;
    }
    int e = q - TL;
    int ti = e / 9, sub = e % 9;
    int r0 = kb + 128 + ti * 128;
    if (sub < 8) {
        // ---- G-update GEMM tile, K=128 ----
        int c0 = sub * 128;
        float acc[8][8] = {};
        for (int s = 0; s < 4; s++) {
            int k0 = kb + s * 32;
            __syncthreads();
            for (int l = 0; l < 4; l++) {
                int f = l * 256 + t;
                int r = f >> 3, c4 = (f & 7) * 4;
                float4 va = *reinterpret_cast<const float4*>(&Ab[(size_t)(r0 + r) * TT + k0 + c4]);
                At[c4 + 0][r] = va.x; At[c4 + 1][r] = va.y; At[c4 + 2][r] = va.z; At[c4 + 3][r] = va.w;
                int kr = f >> 5, cc4 = (f & 31) * 4;
                float4 vb = *reinterpret_cast<const float4*>(&Gb[(size_t)(k0 + kr) * TT + c0 + cc4]);
                *reinterpret_cast<float4*>(&Bs[kr][cc4]) = vb;
            }
            __syncthreads();
#pragma unroll 4
            for (int p = 0; p < 32; p++) {
                float4 a0 = *reinterpret_cast<const float4*>(&At[p][ty * 8]);
                float4 a1 = *reinterpret_cast<const float4*>(&At[p][ty * 8 + 4]);
                float4 b0 = *reinterpret_cast<const float4*>(&Bs[p][tx * 4]);
                float4 b1 = *reinterpret_cast<const float4*>(&Bs[p][tx * 4 + 64]);
                float aa[8] = {a0.x, a0.y, a0.z, a0.w, a1.x, a1.y, a1.z, a1.w};
                float bl[4] = {b0.x, b0.y, b0.z, b0.w};
                float bh[4] = {b1.x, b1.y, b1.z, b1.w};
                for (int i = 0; i < 8; i++) {
                    for (int j = 0; j < 4; j++) acc[i][j] += aa[i] * bl[j];
                    for (int j = 0; j < 4; j++) acc[i][j + 4] += aa[i] * bh[j];
                }
            }
        }
        for (int i = 0; i < 8; i++) {
            int rr = ty * 8 + i;
            float* cp0 = &Gb[(size_t)(r0 + rr) * TT + c0 + tx * 4];
            float4 cv0 = *reinterpret_cast<float4*>(cp0);
            cv0.x -= acc[i][0]; cv0.y -= acc[i][1]; cv0.z -= acc[i][2]; cv0.w -= acc[i][3];
            *reinterpret_cast<float4*>(cp0) = cv0;
            float* cp1 = cp0 + 64;
            float4 cv1 = *reinterpret_cast<float4*>(cp1);
            cv1.x -= acc[i][4]; cv1.y -= acc[i][5]; cv1.z -= acc[i][6]; cv1.w -= acc[i][7];
            *reinterpret_cast<float4*>(cp1) = cv1;
        }
    } else {
        // ---- z-update: z[r0..r0+127] -= L[r0.., kb..kb+127] * z[kb..kb+127] ----
        if (t < 128) zk[t] = zb[beta * TT + kb + t];
        float accz = 0.f;
        for (int s = 0; s < 4; s++) {
            int k0 = kb + s * 32;
            __syncthreads();
            for (int l = 0; l < 4; l++) {
                int f = l * 256 + t;
                int r = f >> 3, c4 = (f & 7) * 4;
                float4 va = *reinterpret_cast<const float4*>(&Ab[(size_t)(r0 + r) * TT + k0 + c4]);
                At[c4 + 0][r] = va.x; At[c4 + 1][r] = va.y; At[c4 + 2][r] = va.z; At[c4 + 3][r] = va.w;
            }
            __syncthreads();
            if (t < 128) {
                for (int qq = 0; qq < 32; qq++) accz += At[qq][t] * zk[s * 32 + qq];
            }
        }
        if (t < 128) zb[beta * TT + r0 + t] -= accz;
    }
}

// ---------------- copy factored diag blocks Dfac -> A (before k_P) ----------------
__global__ __launch_bounds__(256) void k_diagfix128(float* __restrict__ A,
                                                    const float* __restrict__ Dfac) {
    int k = blockIdx.x, bz = blockIdx.y;
    int kb = k * 128;
    float* Ab = A + (size_t)bz * TT * TT;
    const float* Df = Dfac + ((size_t)bz * 8 + k) * 16384;
    int t = threadIdx.x;
    for (int l = 0; l < 64; l++) {
        int e = l * 256 + t; int r = e >> 7, c = e & 127;
        if (c <= r) Ab[(size_t)(kb + r) * TT + kb + c] = Df[r * 128 + c];
    }
}

// ---------------- mean = c + V^T z ----------------
__global__ __launch_bounds__(256) void k_mean(const float* __restrict__ G,
                                              const float* __restrict__ zb,
                                              const float* __restrict__ mc,
                                              float* __restrict__ meanb, int b0) {
    int bz = blockIdx.y; int b = b0 + bz;
    const float* Gb = G + (size_t)bz * TT * TT;
    int i = blockIdx.x * 256 + threadIdx.x;
    float acc = 0.f;
    for (int j = 0; j < TT; j++) acc += Gb[(size_t)j * TT + i] * zb[bz * TT + j];
    meanb[b * TT + i] = mc[0] + acc;
}

// ---------------- cov = Kss - V^T V + JIT*I : 128x128 tiles, XCD-pinned ----------------
__global__ __launch_bounds__(256) void k_cov128(const float* __restrict__ G,
                                                const float* __restrict__ xs,
                                                const int* __restrict__ ite,
                                                const float* __restrict__ lsp,
                                                const float* __restrict__ Bt,
                                                float* __restrict__ A, int b0, int bc) {
    int lin = blockIdx.x;
    int slot = lin & 7, tau = lin >> 3;
    int beta = ((slot - 4 * (tau & 1)) & 7) + (blockIdx.y << 3);
    if (beta >= bc) return;
    int ti, tj; tri_map(tau, ti, tj);
    int b = b0 + beta;
    const float* Gb = G + (size_t)beta * TT * TT;
    float* Ab = A + (size_t)beta * TT * TT;
    int i0 = ti * 128, j0 = tj * 128;
    __shared__ __align__(16) float Va[32][132];
    __shared__ __align__(16) float Vb[32][132];
    __shared__ float sxi[128], sxj[128], Btl[289];
    __shared__ int sei[128], sej[128];
    int t = threadIdx.x, tx = t & 15, ty = t >> 4;
    if (t < 128) { sxi[t] = xs[b * TT + i0 + t]; sei[t] = ite[b * TT + i0 + t]; }
    else { int u = t - 128; sxj[u] = xs[b * TT + j0 + u]; sej[u] = ite[b * TT + j0 + u]; }
    for (int e = t; e < 289; e += 256) Btl[e] = Bt[e];
    float acc[8][8] = {};
    for (int k0 = 0; k0 < TT; k0 += 32) {
        __syncthreads();
        for (int l = 0; l < 4; l++) {
            int f = l * 256 + t;
            int kr = f >> 5, cc4 = (f & 31) * 4;
            *reinterpret_cast<float4*>(&Va[kr][cc4]) =
                *reinterpret_cast<const float4*>(&Gb[(size_t)(k0 + kr) * TT + i0 + cc4]);
            *reinterpret_cast<float4*>(&Vb[kr][cc4]) =
                *reinterpret_cast<const float4*>(&Gb[(size_t)(k0 + kr) * TT + j0 + cc4]);
        }
        __syncthreads();
#pragma unroll 4
        for (int p = 0; p < 32; p++) {
            float4 a0 = *reinterpret_cast<const float4*>(&Va[p][ty * 8]);
            float4 a1 = *reinterpret_cast<const float4*>(&Va[p][ty * 8 + 4]);
            float4 b0 = *reinterpret_cast<const float4*>(&Vb[p][tx * 4]);
            float4 b1 = *reinterpret_cast<const float4*>(&Vb[p][tx * 4 + 64]);
            float aa[8] = {a0.x, a0.y, a0.z, a0.w, a1.x, a1.y, a1.z, a1.w};
            float bl[4] = {b0.x, b0.y, b0.z, b0.w};
            float bh[4] = {b1.x, b1.y, b1.z, b1.w};
            for (int i = 0; i < 8; i++) {
                for (int j = 0; j < 4; j++) acc[i][j] += aa[i] * bl[j];
                for (int j = 0; j < 4; j++) acc[i][j + 4] += aa[i] * bh[j];
            }
        }
    }
    float invls = 1.0f / lsp[0];
    for (int i = 0; i < 8; i++) {
        int ri = ty * 8 + i; int gi = i0 + ri;
        float xi = sxi[ri]; int ci = sei[ri] * 17;
        float vo[8];
        for (int j = 0; j < 4; j++) {
            int rj = tx * 4 + j; int gj = j0 + rj;
            float d = (xi - sxj[rj]) * invls;
            float v = expf(-0.5f * d * d) * Btl[ci + sej[rj]] - acc[i][j];
            if (gi == gj) v += JIT;
            vo[j] = v;
        }
        for (int j = 0; j < 4; j++) {
            int rj = 64 + tx * 4 + j; int gj = j0 + rj;
            float d = (xi - sxj[rj]) * invls;
            float v = expf(-0.5f * d * d) * Btl[ci + sej[rj]] - acc[i][j + 4];
            if (gi == gj) v += JIT;
            vo[j + 4] = v;
        }
        float* cp = &Ab[(size_t)gi * TT + j0 + tx * 4];
        *reinterpret_cast<float4*>(cp) = make_float4(vo[0], vo[1], vo[2], vo[3]);
        *reinterpret_cast<float4*>(cp + 64) = make_float4(vo[4], vo[5], vo[6], vo[7]);
    }
}

// ---------------- P[c][j] = sum_{i>=j, ch(i)=c} Lstar[i][j] ----------------
__global__ __launch_bounds__(256) void k_P(const float* __restrict__ A,
                                           const int* __restrict__ ite,
                                           float* __restrict__ P, int b0) {
    int bz = blockIdx.y; int b = b0 + bz;
    const float* Ab = A + (size_t)bz * TT * TT;
    __shared__ int chl[TT];
    __shared__ float accl[CH * 256];
    int t = threadIdx.x;
    for (int i = t; i < TT; i += 256) chl[i] = ite[b * TT + i];
    for (int c = 0; c < CH; c++) accl[c * 256 + t] = 0.f;
    __syncthreads();
    int j0 = blockIdx.x * 256;
    int j = j0 + t;
    for (int i = j0; i < TT; i++) {
        float v = Ab[(size_t)i * TT + j];
        if (i >= j) accl[chl[i] * 256 + t] += v;
    }
    for (int c = 0; c < CH; c++) P[((size_t)b * CH + c) * TT + j] = accl[c * 256 + t];
}

// ---------------- msum[c] = sum_{ch(i)=c} mean[i] ----------------
__global__ __launch_bounds__(64) void k_msum(const float* __restrict__ meanb,
                                             const int* __restrict__ ite,
                                             float* __restrict__ msum, int b0) {
    int bz = blockIdx.x; int b = b0 + bz;
    __shared__ float pacc[CH][65];
    int t = threadIdx.x;
    for (int c = 0; c < CH; c++) pacc[c][t] = 0.f;
    __syncthreads();
    for (int i = t; i < TT; i += 64) pacc[ite[b * TT + i]][t] += meanb[b * TT + i];
    __syncthreads();
    if (t < CH) {
        float s = 0.f;
        for (int u = 0; u < 64; u++) s += pacc[t][u];
        msum[b * CH + t] = s;
    }
}

// ---------------- feat + classifier head ----------------
__global__ __launch_bounds__(256) void k_featout(const float* __restrict__ P,
                                                 const float* __restrict__ msum,
                                                 const float* __restrict__ eps,
                                                 const float* __restrict__ Wc,
                                                 const float* __restrict__ bc_,
                                                 float* __restrict__ out, int b0, int Btot) {
    int s = blockIdx.x; int b = b0 + blockIdx.y;
    __shared__ float el[TT];
    __shared__ float part[256];
    __shared__ float featl[CH];
    int t = threadIdx.x;
    for (int i = t; i < TT; i += 256) el[i] = eps[((size_t)s * Btot + b) * TT + i];
    __syncthreads();
    int c = t >> 4, seg = t & 15;
    float acc = 0.f;
    const float* Pr = &P[((size_t)b * CH + c) * TT + seg * 64];
    for (int j = 0; j < 64; j++) acc += Pr[j] * el[seg * 64 + j];
    part[t] = acc;
    __syncthreads();
    if (t < CH) {
        float s2 = msum[b * CH + t];
        for (int g = 0; g < 16; g++) s2 += part[t * 16 + g];
        featl[t] = s2 * (1.0f / 64.0f);
    }
    __syncthreads();
    if (t < NCLS) {
        float o = bc_[t];
        for (int c2 = 0; c2 < CH; c2++) o += featl[c2] * Wc[c2 * NCLS + t];
        out[((size_t)s * Btot + b) * NCLS + t] = o;
    }
}

extern "C" void kernel_launch(void* const* d_in, const int* in_sizes, int n_in,
                              void* d_out, int out_size, void* d_ws, size_t ws_size,
                              hipStream_t stream) {
    const float* inputs       = (const float*)d_in[0];
    const float* values       = (const float*)d_in[1];
    const float* test_inputs  = (const float*)d_in[2];
    const float* eps          = (const float*)d_in[3];
    const float* mc           = (const float*)d_in[4];
    const float* ls           = (const float*)d_in[5];
    const float* noise        = (const float*)d_in[6];
    const float* W_task       = (const float*)d_in[7];
    const float* v_task       = (const float*)d_in[8];
    const float* W_clf        = (const float*)d_in[9];
    const float* b_clf        = (const float*)d_in[10];
    const int*   indices      = (const int*)d_in[11];
    const int*   test_indices = (const int*)d_in[12];
    float* out = (float*)d_out;

    int Btot = in_sizes[1] / TT;   // 32

    float* ws = (float*)d_ws;
    size_t off = 0;
    float* Bt    = ws + off; off += 512;
    float* zbuf  = ws + off; off += (size_t)Btot * TT;
    float* meanb = ws + off; off += (size_t)Btot * TT;
    float* Pb    = ws + off; off += (size_t)Btot * CH * TT;
    float* msum  = ws + off; off += (size_t)Btot * CH;
    off = (off + 63) & ~(size_t)63;

    size_t avail = (ws_size / 4 > off) ? (ws_size / 4 - off) : 0;
    size_t per = 2 * (size_t)TT * TT + 8 * 16384;   // A + G + Dfac per batch
    int chunk = (int)(avail / per);
    if (chunk < 1) chunk = 1;
    if (chunk > Btot) chunk = Btot;
    // snap to a power of two so chunks divide Btot evenly (no tiny tail chain)
    if (chunk < Btot) {
        int p2 = 1;
        while (p2 * 2 <= chunk) p2 *= 2;
        chunk = p2;
    }
    float* bigA = ws + off;
    float* bigG = bigA + (size_t)chunk * TT * TT;
    float* Dfac = bigG + (size_t)chunk * TT * TT;

    k_btask<<<1, 256, 0, stream>>>(W_task, v_task, Bt);

    for (int b0 = 0; b0 < Btot; b0 += chunk) {
        int bcc = chunk; if (b0 + bcc > Btot) bcc = Btot - b0;
        int by = (bcc + 7) / 8;

        // ---- build Kxx, G, z ----
        k_build_kxx<<<dim3(8, 8, bcc), 256, 0, stream>>>(inputs, indices, ls, noise, Bt, bigA, b0);
        k_build_g<<<dim3(8, 8, bcc), 256, 0, stream>>>(test_inputs, inputs, test_indices, indices, ls, Bt, bigG, b0);
        k_zinit<<<bcc, 256, 0, stream>>>(values, mc, zbuf, b0);
        // ---- merged chain (NB=128): chol(Kxx) + V = L^{-1}G + z ----
        for (int k = 0; k < 8; k++) {
            int m = 7 - k;
            k_A128<<<dim3(1 + m + 8, bcc), 256, 0, stream>>>(bigA, bigG, zbuf, Dfac, k, m, 1);
            if (m > 0) {
                int nq = m * (m + 1) / 2 + 9 * m;
                k_B128<<<dim3(nq * 8, by), 256, 0, stream>>>(bigA, bigG, zbuf, k, m, bcc, 1);
            }
        }
        // ---- mean = c + V^T z ----
        k_mean<<<dim3(4, bcc), 256, 0, stream>>>(bigG, zbuf, mc, meanb, b0);
        // ---- cov -> A, chol(cov) ----
        k_cov128<<<dim3(36 * 8, by), 256, 0, stream>>>(bigG, test_inputs, test_indices, ls, Bt, bigA, b0, bcc);
        for (int k = 0; k < 8; k++) {
            int m = 7 - k;
            k_A128<<<dim3(1 + m, bcc), 256, 0, stream>>>(bigA, bigA, zbuf, Dfac, k, m, 0);
            if (m > 0) {
                int nq = m * (m + 1) / 2;
                k_B128<<<dim3(nq * 8, by), 256, 0, stream>>>(bigA, bigA, zbuf, k, m, bcc, 0);
            }
        }
        // ---- restore factored diag blocks for k_P ----
        k_diagfix128<<<dim3(8, bcc), 256, 0, stream>>>(bigA, Dfac);
        // ---- pooled sampling + classifier ----
        k_P<<<dim3(4, bcc), 256, 0, stream>>>(bigA, test_indices, Pb, b0);
        k_msum<<<bcc, 64, 0, stream>>>(meanb, test_indices, msum, b0);
        k_featout<<<dim3(SMC, bcc), 256, 0, stream>>>(Pb, msum, eps, W_clf, b_clf, out, b0, Btot);
    }
}

// Round 16
// 10136.366 us; speedup vs baseline: 1.4799x; 1.4799x over previous
//
#include <hip/hip_runtime.h>
#include <math.h>

#define TT 1024
#define CH 16
#define SMC 10
#define NCLS 10
#define JIT 1e-4f

__device__ __forceinline__ void tri_map(int tau, int& ti, int& tj) {
    int i = 0, r = tau;
    while (r >= i + 1) { r -= i + 1; i++; }
    ti = i; tj = r;
}

// ---------------- Btask = W W^T + diag(softplus(v)) ----------------
__global__ __launch_bounds__(256) void k_btask(const float* __restrict__ W,
                                               const float* __restrict__ v,
                                               float* __restrict__ Bt) {
    int t = threadIdx.x;
    for (int e = t; e < 17 * 17; e += 256) {
        int i = e / 17, j = e % 17;
        float s = 0.f;
        for (int r = 0; r < 3; r++) s += W[i * 3 + r] * W[j * 3 + r];
        if (i == j) s += log1pf(expf(v[i]));
        Bt[e] = s;
    }
}

// ---------------- Kxx build (lower 128-blocks) ----------------
__global__ __launch_bounds__(256) void k_build_kxx(const float* __restrict__ x,
                                                   const int* __restrict__ itr,
                                                   const float* __restrict__ lsp,
                                                   const float* __restrict__ noisep,
                                                   const float* __restrict__ Bt,
                                                   float* __restrict__ A, int b0) {
    int bi = blockIdx.x, bj = blockIdx.y, bz = blockIdx.z;
    if (bj > bi) return;
    int b = b0 + bz;
    __shared__ float sxi[128], sxj[128], Btl[289];
    __shared__ int sii[128], sij[128];
    int t = threadIdx.x;
    if (t < 128) { sxi[t] = x[b * TT + bi * 128 + t]; sii[t] = itr[b * TT + bi * 128 + t]; }
    else { int u = t - 128; sxj[u] = x[b * TT + bj * 128 + u]; sij[u] = itr[b * TT + bj * 128 + u]; }
    for (int e = t; e < 289; e += 256) Btl[e] = Bt[e];
    __syncthreads();
    float invls = 1.0f / lsp[0];
    float n2 = noisep[0] * noisep[0] + JIT;
    float* Ab = A + (size_t)bz * TT * TT;
    for (int l = 0; l < 64; l++) {
        int e = l * 256 + t;
        int r = e >> 7, c = e & 127;
        float d = (sxi[r] - sxj[c]) * invls;
        float kv = expf(-0.5f * d * d) * Btl[sii[r] * 17 + sij[c]];
        int gi = bi * 128 + r, gj = bj * 128 + c;
        if (gi == gj) kv += n2;
        Ab[(size_t)gi * TT + gj] = kv;
    }
}

// ---------------- G = Ksx^T build ([train j][test i]) ----------------
__global__ __launch_bounds__(256) void k_build_g(const float* __restrict__ xs,
                                                 const float* __restrict__ x,
                                                 const int* __restrict__ ite,
                                                 const int* __restrict__ itr,
                                                 const float* __restrict__ lsp,
                                                 const float* __restrict__ Bt,
                                                 float* __restrict__ G, int b0) {
    int bj = blockIdx.x, bi = blockIdx.y, bz = blockIdx.z;
    int b = b0 + bz;
    __shared__ float sxr[128], sxc[128], Btl[289];
    __shared__ int sir[128], sic[128];
    int t = threadIdx.x;
    if (t < 128) { sxr[t] = x[b * TT + bj * 128 + t]; sir[t] = itr[b * TT + bj * 128 + t]; }
    else { int u = t - 128; sxc[u] = xs[b * TT + bi * 128 + u]; sic[u] = ite[b * TT + bi * 128 + u]; }
    for (int e = t; e < 289; e += 256) Btl[e] = Bt[e];
    __syncthreads();
    float invls = 1.0f / lsp[0];
    float* Gb = G + (size_t)bz * TT * TT;
    for (int l = 0; l < 64; l++) {
        int e = l * 256 + t;
        int r = e >> 7, c = e & 127;
        float d = (sxc[c] - sxr[r]) * invls;
        float kv = expf(-0.5f * d * d) * Btl[sic[c] * 17 + sir[r]];
        Gb[(size_t)(bj * 128 + r) * TT + bi * 128 + c] = kv;
    }
}

// ---------------- z init: z = y - c ----------------
__global__ __launch_bounds__(256) void k_zinit(const float* __restrict__ values,
                                               const float* __restrict__ mc,
                                               float* __restrict__ zb, int b0) {
    int bz = blockIdx.x, t = threadIdx.x;
    float c0 = mc[0];
    for (int i = t; i < TT; i += 256) zb[bz * TT + i] = values[(size_t)(b0 + bz) * TT + i] - c0;
}

// ---------------- merged chain phase A (NB=64) ----------------
__global__ __launch_bounds__(256) void k_stepA64(float* __restrict__ A,
                                                 float* __restrict__ G,
                                                 float* __restrict__ zb,
                                                 float* __restrict__ Dfac,
                                                 int k, int m, int withG) {
    int bx = blockIdx.x, bz = blockIdx.y;
    float* Ab = A + (size_t)bz * TT * TT;
    float* Gb = G + (size_t)bz * TT * TT;
    int kb = k * 64;
    __shared__ float Ld[64][65];
    __shared__ float WK[64][129];
    __shared__ float invl[64];
    __shared__ float zs[64];
    int t = threadIdx.x;
    for (int l = 0; l < 16; l++) {
        int e = l * 256 + t; int r = e >> 6, c = e & 63;
        Ld[r][c] = Ab[(size_t)(kb + r) * TT + kb + c];
    }
    int jtype = 0, r0 = 0, c0 = 0;
    if (bx >= 1 && bx <= m) {
        jtype = 1; r0 = kb + 64 * bx;
        for (int l = 0; l < 16; l++) {
            int e = l * 256 + t; int r = e >> 6, c = e & 63;
            WK[r][c] = Ab[(size_t)(r0 + r) * TT + kb + c];
        }
    } else if (withG && bx >= m + 1 && bx <= m + 8) {
        jtype = 2; c0 = (bx - m - 1) * 128;
        for (int l = 0; l < 32; l++) {
            int e = l * 256 + t; int r = e >> 7, c = e & 127;
            WK[r][c] = Gb[(size_t)(kb + r) * TT + c0 + c];
        }
    } else if (withG && bx == m + 9) {
        jtype = 3;
        if (t < 64) zs[t] = zb[bz * TT + kb + t];
    }
    __syncthreads();
    for (int j = 0; j < 64; j++) {
        if (t == j) { float d = sqrtf(Ld[j][j]); Ld[j][j] = d; invl[j] = 1.0f / d; }
        __syncthreads();
        float lij = 0.f;
        if (t < 64 && t > j) { lij = Ld[t][j] * invl[j]; Ld[t][j] = lij; }
        __syncthreads();
        if (t < 64 && t > j) {
#pragma unroll 4
            for (int p = j + 1; p <= t; p++) Ld[t][p] -= lij * Ld[p][j];
        }
    }
    __syncthreads();
    if (jtype == 0) {
        if (bx == 0) {
            float* Df = Dfac + ((size_t)bz * 16 + k) * 4096;
            for (int l = 0; l < 16; l++) {
                int e = l * 256 + t; int r = e >> 6, c = e & 63;
                Df[r * 64 + c] = Ld[r][c];
            }
        }
        return;
    }
    if (jtype == 1) {
        if (t < 64) {
            for (int j = 0; j < 64; j++) {
                float xv = WK[t][j] * invl[j];
                WK[t][j] = xv;
#pragma unroll 4
                for (int p = j + 1; p < 64; p++) WK[t][p] -= Ld[p][j] * xv;
            }
        }
        __syncthreads();
        for (int l = 0; l < 16; l++) {
            int e = l * 256 + t; int r = e >> 6, c = e & 63;
            Ab[(size_t)(r0 + r) * TT + kb + c] = WK[r][c];
        }
    } else if (jtype == 2) {
        if (t < 128) {
            for (int j = 0; j < 64; j++) {
                float xv = WK[j][t] * invl[j];
                WK[j][t] = xv;
#pragma unroll 4
                for (int p = j + 1; p < 64; p++) WK[p][t] -= Ld[p][j] * xv;
            }
        }
        __syncthreads();
        for (int l = 0; l < 32; l++) {
            int e = l * 256 + t; int r = e >> 7, c = e & 127;
            Gb[(size_t)(kb + r) * TT + c0 + c] = WK[r][c];
        }
    } else {
        if (t == 0) {
            for (int j = 0; j < 64; j++) {
                float zv = zs[j] * invl[j];
                zs[j] = zv;
#pragma unroll 4
                for (int p = j + 1; p < 64; p++) zs[p] -= Ld[p][j] * zv;
            }
        }
        __syncthreads();
        if (t < 64) zb[bz * TT + kb + t] = zs[t];
    }
}

// ---------------- copy factored diag blocks Dfac -> A (before k_P) ----------------
__global__ __launch_bounds__(256) void k_diagfix64(float* __restrict__ A,
                                                   const float* __restrict__ Dfac) {
    int k = blockIdx.x, bz = blockIdx.y;
    int kb = k * 64;
    float* Ab = A + (size_t)bz * TT * TT;
    const float* Df = Dfac + ((size_t)bz * 16 + k) * 4096;
    int t = threadIdx.x;
    for (int l = 0; l < 16; l++) {
        int e = l * 256 + t; int r = e >> 6, c = e & 63;
        if (c <= r) Ab[(size_t)(kb + r) * TT + kb + c] = Df[r * 64 + c];
    }
}

// ---------------- merged chain phase B (K=64 trailing updates), XCD-pinned ----------------
__global__ __launch_bounds__(256) void k_stepB64(float* __restrict__ A,
                                                 float* __restrict__ G,
                                                 float* __restrict__ zb,
                                                 int k, int m, int bc, int withG) {
    int lin = blockIdx.x;
    int slot = lin & 7, q = lin >> 3;
    int beta = ((slot - 4 * (q & 1)) & 7) + (blockIdx.y << 3);
    if (beta >= bc) return;
    float* Ab = A + (size_t)beta * TT * TT;
    float* Gb = G + (size_t)beta * TT * TT;
    int kb = k * 64;
    int nt = (64 * m + 127) / 128;
    int TL = nt * (nt + 1) / 2;
    __shared__ __align__(16) float At[32][132];
    __shared__ __align__(16) float Bs[32][132];
    __shared__ float zk[64];
    int t = threadIdx.x, tx = t & 15, ty = t >> 4;
    if (q < TL) {
        int ti, tj; tri_map(q, ti, tj);
        int base = kb + 64;
        int r0 = base + ti * 128, c0 = base + tj * 128;
        int rvi = TT - r0; if (rvi > 128) rvi = 128;
        int rvj = TT - c0; if (rvj > 128) rvj = 128;
        float acc[8][8] = {};
        for (int s = 0; s < 2; s++) {
            int k0 = kb + s * 32;
            __syncthreads();
            for (int l = 0; l < 4; l++) {
                int f = l * 256 + t;
                int r = f >> 3, c4 = (f & 7) * 4;
                float4 va = make_float4(0.f, 0.f, 0.f, 0.f), vb = make_float4(0.f, 0.f, 0.f, 0.f);
                if (r < rvi) va = *reinterpret_cast<const float4*>(&Ab[(size_t)(r0 + r) * TT + k0 + c4]);
                if (r < rvj) vb = *reinterpret_cast<const float4*>(&Ab[(size_t)(c0 + r) * TT + k0 + c4]);
                At[c4 + 0][r] = va.x; At[c4 + 1][r] = va.y; At[c4 + 2][r] = va.z; At[c4 + 3][r] = va.w;
                Bs[c4 + 0][r] = vb.x; Bs[c4 + 1][r] = vb.y; Bs[c4 + 2][r] = vb.z; Bs[c4 + 3][r] = vb.w;
            }
            __syncthreads();
#pragma unroll 4
            for (int p = 0; p < 32; p++) {
                float4 a0 = *reinterpret_cast<const float4*>(&At[p][ty * 8]);
                float4 a1 = *reinterpret_cast<const float4*>(&At[p][ty * 8 + 4]);
                float4 b0 = *reinterpret_cast<const float4*>(&Bs[p][tx * 4]);
                float4 b1 = *reinterpret_cast<const float4*>(&Bs[p][tx * 4 + 64]);
                float aa[8] = {a0.x, a0.y, a0.z, a0.w, a1.x, a1.y, a1.z, a1.w};
                float bl[4] = {b0.x, b0.y, b0.z, b0.w};
                float bh[4] = {b1.x, b1.y, b1.z, b1.w};
                for (int i = 0; i < 8; i++) {
                    for (int j = 0; j < 4; j++) acc[i][j] += aa[i] * bl[j];
                    for (int j = 0; j < 4; j++) acc[i][j + 4] += aa[i] * bh[j];
                }
            }
        }
        if (tx * 4 >= rvj) return;
        for (int i = 0; i < 8; i++) {
            int rr = ty * 8 + i;
            if (rr >= rvi) break;
            float* cp0 = &Ab[(size_t)(r0 + rr) * TT + c0 + tx * 4];
            float4 cv0 = *reinterpret_cast<float4*>(cp0);
            cv0.x -= acc[i][0]; cv0.y -= acc[i][1]; cv0.z -= acc[i][2]; cv0.w -= acc[i][3];
            *reinterpret_cast<float4*>(cp0) = cv0;
            if (rvj > 64) {
                float* cp1 = cp0 + 64;
                float4 cv1 = *reinterpret_cast<float4*>(cp1);
                cv1.x -= acc[i][4]; cv1.y -= acc[i][5]; cv1.z -= acc[i][6]; cv1.w -= acc[i][7];
                *reinterpret_cast<float4*>(cp1) = cv1;
            }
        }
        return;
    }
    int e = q - TL;
    int ti = e / 9, sub = e % 9;
    int r0 = kb + 64 + ti * 128;
    int rvi = TT - r0; if (rvi > 128) rvi = 128;
    if (sub < 8) {
        int c0 = sub * 128;
        float acc[8][8] = {};
        for (int s = 0; s < 2; s++) {
            int k0 = kb + s * 32;
            __syncthreads();
            for (int l = 0; l < 4; l++) {
                int f = l * 256 + t;
                int r = f >> 3, c4 = (f & 7) * 4;
                float4 va = make_float4(0.f, 0.f, 0.f, 0.f);
                if (r < rvi) va = *reinterpret_cast<const float4*>(&Ab[(size_t)(r0 + r) * TT + k0 + c4]);
                At[c4 + 0][r] = va.x; At[c4 + 1][r] = va.y; At[c4 + 2][r] = va.z; At[c4 + 3][r] = va.w;
                int kr = f >> 5, cc4 = (f & 31) * 4;
                float4 vb = *reinterpret_cast<const float4*>(&Gb[(size_t)(k0 + kr) * TT + c0 + cc4]);
                *reinterpret_cast<float4*>(&Bs[kr][cc4]) = vb;
            }
            __syncthreads();
#pragma unroll 4
            for (int p = 0; p < 32; p++) {
                float4 a0 = *reinterpret_cast<const float4*>(&At[p][ty * 8]);
                float4 a1 = *reinterpret_cast<const float4*>(&At[p][ty * 8 + 4]);
                float4 b0 = *reinterpret_cast<const float4*>(&Bs[p][tx * 4]);
                float4 b1 = *reinterpret_cast<const float4*>(&Bs[p][tx * 4 + 64]);
                float aa[8] = {a0.x, a0.y, a0.z, a0.w, a1.x, a1.y, a1.z, a1.w};
                float bl[4] = {b0.x, b0.y, b0.z, b0.w};
                float bh[4] = {b1.x, b1.y, b1.z, b1.w};
                for (int i = 0; i < 8; i++) {
                    for (int j = 0; j < 4; j++) acc[i][j] += aa[i] * bl[j];
                    for (int j = 0; j < 4; j++) acc[i][j + 4] += aa[i] * bh[j];
                }
            }
        }
        for (int i = 0; i < 8; i++) {
            int rr = ty * 8 + i;
            if (rr >= rvi) break;
            float* cp0 = &Gb[(size_t)(r0 + rr) * TT + c0 + tx * 4];
            float4 cv0 = *reinterpret_cast<float4*>(cp0);
            cv0.x -= acc[i][0]; cv0.y -= acc[i][1]; cv0.z -= acc[i][2]; cv0.w -= acc[i][3];
            *reinterpret_cast<float4*>(cp0) = cv0;
            float* cp1 = cp0 + 64;
            float4 cv1 = *reinterpret_cast<float4*>(cp1);
            cv1.x -= acc[i][4]; cv1.y -= acc[i][5]; cv1.z -= acc[i][6]; cv1.w -= acc[i][7];
            *reinterpret_cast<float4*>(cp1) = cv1;
        }
    } else {
        if (t < 64) zk[t] = zb[beta * TT + kb + t];
        float accz = 0.f;
        for (int s = 0; s < 2; s++) {
            int k0 = kb + s * 32;
            __syncthreads();
            for (int l = 0; l < 4; l++) {
                int f = l * 256 + t;
                int r = f >> 3, c4 = (f & 7) * 4;
                float4 va = make_float4(0.f, 0.f, 0.f, 0.f);
                if (r < rvi) va = *reinterpret_cast<const float4*>(&Ab[(size_t)(r0 + r) * TT + k0 + c4]);
                At[c4 + 0][r] = va.x; At[c4 + 1][r] = va.y; At[c4 + 2][r] = va.z; At[c4 + 3][r] = va.w;
            }
            __syncthreads();
            if (t < 128) {
                for (int qq = 0; qq < 32; qq++) accz += At[qq][t] * zk[s * 32 + qq];
            }
        }
        if (t < rvi) zb[beta * TT + r0 + t] -= accz;
    }
}

// ---------------- cov = Kss - V^T V + JIT*I : 64x64 tiles, XCD-pinned ----------------
// Diagonal tiles also compute mean = c + V^T z (fuses the old k_mean).
__global__ __launch_bounds__(256) void k_cov64(const float* __restrict__ G,
                                               const float* __restrict__ xs,
                                               const int* __restrict__ ite,
                                               const float* __restrict__ lsp,
                                               const float* __restrict__ Bt,
                                               float* __restrict__ A,
                                               const float* __restrict__ zb,
                                               const float* __restrict__ mc,
                                               float* __restrict__ meanb,
                                               int b0, int bc) {
    int lin = blockIdx.x;
    int slot = lin & 7, tau = lin >> 3;
    int beta = ((slot - 4 * (tau & 1)) & 7) + (blockIdx.y << 3);
    if (beta >= bc) return;
    int ti, tj; tri_map(tau, ti, tj);
    int b = b0 + beta;
    const float* Gb = G + (size_t)beta * TT * TT;
    float* Ab = A + (size_t)beta * TT * TT;
    int i0 = ti * 64, j0 = tj * 64;
    __shared__ __align__(16) float Va[32][68];
    __shared__ __align__(16) float Vb[32][68];
    __shared__ float sxi[64], sxj[64], Btl[289], zs[32];
    __shared__ int sei[64], sej[64];
    int t = threadIdx.x, tx = t & 15, ty = t >> 4;
    if (t < 64) { sxi[t] = xs[b * TT + i0 + t]; sei[t] = ite[b * TT + i0 + t]; }
    else if (t < 128) { int u = t - 64; sxj[u] = xs[b * TT + j0 + u]; sej[u] = ite[b * TT + j0 + u]; }
    for (int e = t; e < 289; e += 256) Btl[e] = Bt[e];
    bool diag = (ti == tj);
    float acc[4][4] = {};
    float macc[4] = {0.f, 0.f, 0.f, 0.f};
    for (int k0 = 0; k0 < TT; k0 += 32) {
        __syncthreads();
        for (int l = 0; l < 2; l++) {
            int f = l * 256 + t;
            int kr = f >> 4, cc4 = (f & 15) * 4;
            *reinterpret_cast<float4*>(&Va[kr][cc4]) =
                *reinterpret_cast<const float4*>(&Gb[(size_t)(k0 + kr) * TT + i0 + cc4]);
            *reinterpret_cast<float4*>(&Vb[kr][cc4]) =
                *reinterpret_cast<const float4*>(&Gb[(size_t)(k0 + kr) * TT + j0 + cc4]);
        }
        if (diag && t < 32) zs[t] = zb[beta * TT + k0 + t];
        __syncthreads();
#pragma unroll 4
        for (int p = 0; p < 32; p++) {
            float4 av = *reinterpret_cast<const float4*>(&Va[p][ty * 4]);
            float4 bv = *reinterpret_cast<const float4*>(&Vb[p][tx * 4]);
            float aa[4] = {av.x, av.y, av.z, av.w};
            float bb[4] = {bv.x, bv.y, bv.z, bv.w};
            for (int i = 0; i < 4; i++)
                for (int j = 0; j < 4; j++) acc[i][j] += aa[i] * bb[j];
        }
        if (diag && ty == 0) {
#pragma unroll 4
            for (int p = 0; p < 32; p++) {
                float zv = zs[p];
                float4 av = *reinterpret_cast<const float4*>(&Va[p][tx * 4]);
                macc[0] += av.x * zv; macc[1] += av.y * zv;
                macc[2] += av.z * zv; macc[3] += av.w * zv;
            }
        }
    }
    float invls = 1.0f / lsp[0];
    for (int i = 0; i < 4; i++) {
        int ri = ty * 4 + i; int gi = i0 + ri;
        float xi = sxi[ri]; int ci = sei[ri] * 17;
        float vo[4];
        for (int j = 0; j < 4; j++) {
            int rj = tx * 4 + j; int gj = j0 + rj;
            float d = (xi - sxj[rj]) * invls;
            float v = expf(-0.5f * d * d) * Btl[ci + sej[rj]] - acc[i][j];
            if (gi == gj) v += JIT;
            vo[j] = v;
        }
        *reinterpret_cast<float4*>(&Ab[(size_t)gi * TT + j0 + tx * 4]) =
            make_float4(vo[0], vo[1], vo[2], vo[3]);
    }
    if (diag && ty == 0) {
        float c0 = mc[0];
        for (int j = 0; j < 4; j++)
            meanb[(size_t)b * TT + i0 + tx * 4 + j] = c0 + macc[j];
    }
}

// ---------------- P[c][j] = sum_{i>=j, ch(i)=c} Lstar[i][j] ----------------
__global__ __launch_bounds__(256) void k_P(const float* __restrict__ A,
                                           const int* __restrict__ ite,
                                           float* __restrict__ P, int b0) {
    int bz = blockIdx.y; int b = b0 + bz;
    const float* Ab = A + (size_t)bz * TT * TT;
    __shared__ int chl[TT];
    __shared__ float accl[CH * 256];
    int t = threadIdx.x;
    for (int i = t; i < TT; i += 256) chl[i] = ite[b * TT + i];
    for (int c = 0; c < CH; c++) accl[c * 256 + t] = 0.f;
    __syncthreads();
    int j0 = blockIdx.x * 256;
    int j = j0 + t;
    for (int i = j0; i < TT; i++) {
        float v = Ab[(size_t)i * TT + j];
        if (i >= j) accl[chl[i] * 256 + t] += v;
    }
    for (int c = 0; c < CH; c++) P[((size_t)b * CH + c) * TT + j] = accl[c * 256 + t];
}

// ---------------- msum[c] = sum_{ch(i)=c} mean[i] ----------------
__global__ __launch_bounds__(64) void k_msum(const float* __restrict__ meanb,
                                             const int* __restrict__ ite,
                                             float* __restrict__ msum, int b0) {
    int bz = blockIdx.x; int b = b0 + bz;
    __shared__ float pacc[CH][65];
    int t = threadIdx.x;
    for (int c = 0; c < CH; c++) pacc[c][t] = 0.f;
    __syncthreads();
    for (int i = t; i < TT; i += 64) pacc[ite[b * TT + i]][t] += meanb[b * TT + i];
    __syncthreads();
    if (t < CH) {
        float s = 0.f;
        for (int u = 0; u < 64; u++) s += pacc[t][u];
        msum[b * CH + t] = s;
    }
}

// ---------------- feat + classifier head ----------------
__global__ __launch_bounds__(256) void k_featout(const float* __restrict__ P,
                                                 const float* __restrict__ msum,
                                                 const float* __restrict__ eps,
                                                 const float* __restrict__ Wc,
                                                 const float* __restrict__ bc_,
                                                 float* __restrict__ out, int b0, int Btot) {
    int s = blockIdx.x; int b = b0 + blockIdx.y;
    __shared__ float el[TT];
    __shared__ float part[256];
    __shared__ float featl[CH];
    int t = threadIdx.x;
    for (int i = t; i < TT; i += 256) el[i] = eps[((size_t)s * Btot + b) * TT + i];
    __syncthreads();
    int c = t >> 4, seg = t & 15;
    float acc = 0.f;
    const float* Pr = &P[((size_t)b * CH + c) * TT + seg * 64];
    for (int j = 0; j < 64; j++) acc += Pr[j] * el[seg * 64 + j];
    part[t] = acc;
    __syncthreads();
    if (t < CH) {
        float s2 = msum[b * CH + t];
        for (int g = 0; g < 16; g++) s2 += part[t * 16 + g];
        featl[t] = s2 * (1.0f / 64.0f);
    }
    __syncthreads();
    if (t < NCLS) {
        float o = bc_[t];
        for (int c2 = 0; c2 < CH; c2++) o += featl[c2] * Wc[c2 * NCLS + t];
        out[((size_t)s * Btot + b) * NCLS + t] = o;
    }
}

extern "C" void kernel_launch(void* const* d_in, const int* in_sizes, int n_in,
                              void* d_out, int out_size, void* d_ws, size_t ws_size,
                              hipStream_t stream) {
    const float* inputs       = (const float*)d_in[0];
    const float* values       = (const float*)d_in[1];
    const float* test_inputs  = (const float*)d_in[2];
    const float* eps          = (const float*)d_in[3];
    const float* mc           = (const float*)d_in[4];
    const float* ls           = (const float*)d_in[5];
    const float* noise        = (const float*)d_in[6];
    const float* W_task       = (const float*)d_in[7];
    const float* v_task       = (const float*)d_in[8];
    const float* W_clf        = (const float*)d_in[9];
    const float* b_clf        = (const float*)d_in[10];
    const int*   indices      = (const int*)d_in[11];
    const int*   test_indices = (const int*)d_in[12];
    float* out = (float*)d_out;

    int Btot = in_sizes[1] / TT;   // 32

    float* ws = (float*)d_ws;
    size_t off = 0;
    float* Bt    = ws + off; off += 512;
    float* zbuf  = ws + off; off += (size_t)Btot * TT;
    float* meanb = ws + off; off += (size_t)Btot * TT;
    float* Pb    = ws + off; off += (size_t)Btot * CH * TT;
    float* msum  = ws + off; off += (size_t)Btot * CH;
    off = (off + 63) & ~(size_t)63;

    size_t avail = (ws_size / 4 > off) ? (ws_size / 4 - off) : 0;
    size_t per = 2 * (size_t)TT * TT + 16 * 4096;   // A + G + Dfac per batch
    int chunk = (int)(avail / per);
    if (chunk < 1) chunk = 1;
    if (chunk > Btot) chunk = Btot;
    float* bigA = ws + off;
    float* bigG = bigA + (size_t)chunk * TT * TT;
    float* Dfac = bigG + (size_t)chunk * TT * TT;

    k_btask<<<1, 256, 0, stream>>>(W_task, v_task, Bt);

    for (int b0 = 0; b0 < Btot; b0 += chunk) {
        int bcc = chunk; if (b0 + bcc > Btot) bcc = Btot - b0;
        int by = (bcc + 7) / 8;

        // ---- build Kxx, G, z ----
        k_build_kxx<<<dim3(8, 8, bcc), 256, 0, stream>>>(inputs, indices, ls, noise, Bt, bigA, b0);
        k_build_g<<<dim3(8, 8, bcc), 256, 0, stream>>>(test_inputs, inputs, test_indices, indices, ls, Bt, bigG, b0);
        k_zinit<<<bcc, 256, 0, stream>>>(values, mc, zbuf, b0);
        // ---- merged chain: chol(Kxx) + V = L^{-1}G + z ----
        for (int k = 0; k < 16; k++) {
            int m = 15 - k;
            k_stepA64<<<dim3(m + 10, bcc), 256, 0, stream>>>(bigA, bigG, zbuf, Dfac, k, m, 1);
            int nt = (64 * m + 127) / 128;
            int Q = nt * (nt + 1) / 2 + nt * 9;
            if (m > 0) k_stepB64<<<dim3(Q * 8, by), 256, 0, stream>>>(bigA, bigG, zbuf, k, m, bcc, 1);
        }
        // ---- cov -> A (64x64 tiles) + fused mean = c + V^T z ----
        k_cov64<<<dim3(136 * 8, by), 256, 0, stream>>>(bigG, test_inputs, test_indices, ls, Bt,
                                                       bigA, zbuf, mc, meanb, b0, bcc);
        // ---- chol(cov) chain ----
        for (int k = 0; k < 16; k++) {
            int m = 15 - k;
            k_stepA64<<<dim3(m + 1, bcc), 256, 0, stream>>>(bigA, bigA, zbuf, Dfac, k, m, 0);
            int nt = (64 * m + 127) / 128;
            int Q = nt * (nt + 1) / 2;
            if (m > 0) k_stepB64<<<dim3(Q * 8, by), 256, 0, stream>>>(bigA, bigA, zbuf, k, m, bcc, 0);
        }
        // ---- restore factored diag blocks for k_P ----
        k_diagfix64<<<dim3(16, bcc), 256, 0, stream>>>(bigA, Dfac);
        // ---- pooled sampling + classifier ----
        k_P<<<dim3(4, bcc), 256, 0, stream>>>(bigA, test_indices, Pb, b0);
        k_msum<<<bcc, 64, 0, stream>>>(meanb, test_indices, msum, b0);
        k_featout<<<dim3(SMC, bcc), 256, 0, stream>>>(Pb, msum, eps, W_clf, b_clf, out, b0, Btot);
    }
}

// Round 17
// 9589.525 us; speedup vs baseline: 1.5643x; 1.0570x over previous
//
#include <hip/hip_runtime.h>
#include <math.h>

#define TT 1024
#define CH 16
#define SMC 10
#define NCLS 10
#define JIT 1e-4f

__device__ __forceinline__ void tri_map(int tau, int& ti, int& tj) {
    int i = 0, r = tau;
    while (r >= i + 1) { r -= i + 1; i++; }
    ti = i; tj = r;
}

// ---------------- Btask = W W^T + diag(softplus(v)) ----------------
__global__ __launch_bounds__(256) void k_btask(const float* __restrict__ W,
                                               const float* __restrict__ v,
                                               float* __restrict__ Bt) {
    int t = threadIdx.x;
    for (int e = t; e < 17 * 17; e += 256) {
        int i = e / 17, j = e % 17;
        float s = 0.f;
        for (int r = 0; r < 3; r++) s += W[i * 3 + r] * W[j * 3 + r];
        if (i == j) s += log1pf(expf(v[i]));
        Bt[e] = s;
    }
}

// ---------------- Kxx build (lower 128-blocks) ----------------
__global__ __launch_bounds__(256) void k_build_kxx(const float* __restrict__ x,
                                                   const int* __restrict__ itr,
                                                   const float* __restrict__ lsp,
                                                   const float* __restrict__ noisep,
                                                   const float* __restrict__ Bt,
                                                   float* __restrict__ A, int b0) {
    int bi = blockIdx.x, bj = blockIdx.y, bz = blockIdx.z;
    if (bj > bi) return;
    int b = b0 + bz;
    __shared__ float sxi[128], sxj[128], Btl[289];
    __shared__ int sii[128], sij[128];
    int t = threadIdx.x;
    if (t < 128) { sxi[t] = x[b * TT + bi * 128 + t]; sii[t] = itr[b * TT + bi * 128 + t]; }
    else { int u = t - 128; sxj[u] = x[b * TT + bj * 128 + u]; sij[u] = itr[b * TT + bj * 128 + u]; }
    for (int e = t; e < 289; e += 256) Btl[e] = Bt[e];
    __syncthreads();
    float invls = 1.0f / lsp[0];
    float n2 = noisep[0] * noisep[0] + JIT;
    float* Ab = A + (size_t)bz * TT * TT;
    for (int l = 0; l < 64; l++) {
        int e = l * 256 + t;
        int r = e >> 7, c = e & 127;
        float d = (sxi[r] - sxj[c]) * invls;
        float kv = expf(-0.5f * d * d) * Btl[sii[r] * 17 + sij[c]];
        int gi = bi * 128 + r, gj = bj * 128 + c;
        if (gi == gj) kv += n2;
        Ab[(size_t)gi * TT + gj] = kv;
    }
}

// ---------------- G = Ksx^T build ([train j][test i]) ----------------
__global__ __launch_bounds__(256) void k_build_g(const float* __restrict__ xs,
                                                 const float* __restrict__ x,
                                                 const int* __restrict__ ite,
                                                 const int* __restrict__ itr,
                                                 const float* __restrict__ lsp,
                                                 const float* __restrict__ Bt,
                                                 float* __restrict__ G, int b0) {
    int bj = blockIdx.x, bi = blockIdx.y, bz = blockIdx.z;
    int b = b0 + bz;
    __shared__ float sxr[128], sxc[128], Btl[289];
    __shared__ int sir[128], sic[128];
    int t = threadIdx.x;
    if (t < 128) { sxr[t] = x[b * TT + bj * 128 + t]; sir[t] = itr[b * TT + bj * 128 + t]; }
    else { int u = t - 128; sxc[u] = xs[b * TT + bi * 128 + u]; sic[u] = ite[b * TT + bi * 128 + u]; }
    for (int e = t; e < 289; e += 256) Btl[e] = Bt[e];
    __syncthreads();
    float invls = 1.0f / lsp[0];
    float* Gb = G + (size_t)bz * TT * TT;
    for (int l = 0; l < 64; l++) {
        int e = l * 256 + t;
        int r = e >> 7, c = e & 127;
        float d = (sxc[c] - sxr[r]) * invls;
        float kv = expf(-0.5f * d * d) * Btl[sic[c] * 17 + sir[r]];
        Gb[(size_t)(bj * 128 + r) * TT + bi * 128 + c] = kv;
    }
}

// ---------------- z init: z = y - c ----------------
__global__ __launch_bounds__(256) void k_zinit(const float* __restrict__ values,
                                               const float* __restrict__ mc,
                                               float* __restrict__ zb, int b0) {
    int bz = blockIdx.x, t = threadIdx.x;
    float c0 = mc[0];
    for (int i = t; i < TT; i += 256) zb[bz * TT + i] = values[(size_t)(b0 + bz) * TT + i] - c0;
}

// ---------------- seed: factor diag block 0 -> Dfac[0] ----------------
__global__ __launch_bounds__(256) void k_factor0(const float* __restrict__ A,
                                                 float* __restrict__ Dfac) {
    int bz = blockIdx.x;
    const float* Ab = A + (size_t)bz * TT * TT;
    __shared__ float Ld[64][65];
    __shared__ float invl[64];
    int t = threadIdx.x;
    for (int l = 0; l < 16; l++) {
        int e = l * 256 + t; int r = e >> 6, c = e & 63;
        Ld[r][c] = Ab[(size_t)r * TT + c];
    }
    __syncthreads();
    for (int j = 0; j < 64; j++) {
        if (t == j) { float d = sqrtf(Ld[j][j]); Ld[j][j] = d; invl[j] = 1.0f / d; }
        __syncthreads();
        float lij = 0.f;
        if (t < 64 && t > j) { lij = Ld[t][j] * invl[j]; Ld[t][j] = lij; }
        __syncthreads();
        if (t < 64 && t > j) {
#pragma unroll 4
            for (int p = j + 1; p <= t; p++) Ld[t][p] -= lij * Ld[p][j];
        }
    }
    __syncthreads();
    float* Df = Dfac + (size_t)bz * 16 * 4096;
    for (int l = 0; l < 16; l++) {
        int e = l * 256 + t; int r = e >> 6, c = e & 63;
        Df[r * 64 + c] = Ld[r][c];
    }
}

// ---------------- phase A: pure solves, diag loaded FACTORED from Dfac ----------------
// bx < m: A-panel TRSM; withG: bx in [m,m+8): G col-tile; bx == m+8: z.
__global__ __launch_bounds__(256) void k_solveA(float* __restrict__ A,
                                                float* __restrict__ G,
                                                float* __restrict__ zb,
                                                const float* __restrict__ Dfac,
                                                int k, int m, int withG) {
    int bx = blockIdx.x, bz = blockIdx.y;
    float* Ab = A + (size_t)bz * TT * TT;
    float* Gb = G + (size_t)bz * TT * TT;
    int kb = k * 64;
    __shared__ float Ld[64][65];
    __shared__ float WK[64][129];
    __shared__ float invl[64];
    __shared__ float zs[64];
    int t = threadIdx.x;
    const float* Df = Dfac + ((size_t)bz * 16 + k) * 4096;
    for (int l = 0; l < 16; l++) {
        int e = l * 256 + t; int r = e >> 6, c = e & 63;
        Ld[r][c] = Df[r * 64 + c];
    }
    int jtype, r0 = 0, c0 = 0;
    if (bx < m) {
        jtype = 1; r0 = kb + 64 * (bx + 1);
        for (int l = 0; l < 16; l++) {
            int e = l * 256 + t; int r = e >> 6, c = e & 63;
            WK[r][c] = Ab[(size_t)(r0 + r) * TT + kb + c];
        }
    } else if (withG && bx < m + 8) {
        jtype = 2; c0 = (bx - m) * 128;
        for (int l = 0; l < 32; l++) {
            int e = l * 256 + t; int r = e >> 7, c = e & 127;
            WK[r][c] = Gb[(size_t)(kb + r) * TT + c0 + c];
        }
    } else {
        jtype = 3;
        if (t < 64) zs[t] = zb[bz * TT + kb + t];
    }
    __syncthreads();
    if (t < 64) invl[t] = 1.0f / Ld[t][t];
    __syncthreads();
    if (jtype == 1) {
        if (t < 64) {
            for (int j = 0; j < 64; j++) {
                float xv = WK[t][j] * invl[j];
                WK[t][j] = xv;
#pragma unroll 4
                for (int p = j + 1; p < 64; p++) WK[t][p] -= Ld[p][j] * xv;
            }
        }
        __syncthreads();
        for (int l = 0; l < 16; l++) {
            int e = l * 256 + t; int r = e >> 6, c = e & 63;
            Ab[(size_t)(r0 + r) * TT + kb + c] = WK[r][c];
        }
    } else if (jtype == 2) {
        if (t < 128) {
            for (int j = 0; j < 64; j++) {
                float xv = WK[j][t] * invl[j];
                WK[j][t] = xv;
#pragma unroll 4
                for (int p = j + 1; p < 64; p++) WK[p][t] -= Ld[p][j] * xv;
            }
        }
        __syncthreads();
        for (int l = 0; l < 32; l++) {
            int e = l * 256 + t; int r = e >> 7, c = e & 127;
            Gb[(size_t)(kb + r) * TT + c0 + c] = WK[r][c];
        }
    } else {
        if (t == 0) {
            for (int j = 0; j < 64; j++) {
                float zv = zs[j] * invl[j];
                zs[j] = zv;
#pragma unroll 4
                for (int p = j + 1; p < 64; p++) zs[p] -= Ld[p][j] * zv;
            }
        }
        __syncthreads();
        if (t < 64) zb[bz * TT + kb + t] = zs[t];
    }
}

// ---------------- copy factored diag blocks Dfac -> A (before k_P) ----------------
__global__ __launch_bounds__(256) void k_diagfix64(float* __restrict__ A,
                                                   const float* __restrict__ Dfac) {
    int k = blockIdx.x, bz = blockIdx.y;
    int kb = k * 64;
    float* Ab = A + (size_t)bz * TT * TT;
    const float* Df = Dfac + ((size_t)bz * 16 + k) * 4096;
    int t = threadIdx.x;
    for (int l = 0; l < 16; l++) {
        int e = l * 256 + t; int r = e >> 6, c = e & 63;
        if (c <= r) Ab[(size_t)(kb + r) * TT + kb + c] = Df[r * 64 + c];
    }
}

// ---------------- phase B: SYRK + G/z updates + NEXT-STEP diag factor, XCD-pinned ----------------
// q < TL: SYRK tile (q==0 skips the diag(k+1) 64x64 sub-block writes);
// TL <= q < TL+gz: G-update / z-update; q == last: factor diag(k+1) -> Dfac[k+1].
__global__ __launch_bounds__(256) void k_stepB64(float* __restrict__ A,
                                                 float* __restrict__ G,
                                                 float* __restrict__ zb,
                                                 float* __restrict__ Dfac,
                                                 int k, int m, int bc, int withG) {
    int lin = blockIdx.x;
    int slot = lin & 7, q = lin >> 3;
    int beta = ((slot - 4 * (q & 1)) & 7) + (blockIdx.y << 3);
    if (beta >= bc) return;
    float* Ab = A + (size_t)beta * TT * TT;
    float* Gb = G + (size_t)beta * TT * TT;
    int kb = k * 64;
    int nt = (64 * m + 127) / 128;
    int TL = nt * (nt + 1) / 2;
    int gz = withG ? 9 * nt : 0;
    __shared__ __align__(16) float sm[8448];
    float (*At)[132] = reinterpret_cast<float (*)[132]>(sm);
    float (*Bs)[132] = reinterpret_cast<float (*)[132]>(sm + 4224);
    float (*FLd)[65] = reinterpret_cast<float (*)[65]>(sm);
    float (*FPn)[65] = reinterpret_cast<float (*)[65]>(sm + 4160);
    __shared__ float zk[64];
    __shared__ float finv[64];
    int t = threadIdx.x, tx = t & 15, ty = t >> 4;
    if (q < TL) {
        int ti, tj; tri_map(q, ti, tj);
        int base = kb + 64;
        int r0 = base + ti * 128, c0 = base + tj * 128;
        int rvi = TT - r0; if (rvi > 128) rvi = 128;
        int rvj = TT - c0; if (rvj > 128) rvj = 128;
        float acc[8][8] = {};
        for (int s = 0; s < 2; s++) {
            int k0 = kb + s * 32;
            __syncthreads();
            for (int l = 0; l < 4; l++) {
                int f = l * 256 + t;
                int r = f >> 3, c4 = (f & 7) * 4;
                float4 va = make_float4(0.f, 0.f, 0.f, 0.f), vb = make_float4(0.f, 0.f, 0.f, 0.f);
                if (r < rvi) va = *reinterpret_cast<const float4*>(&Ab[(size_t)(r0 + r) * TT + k0 + c4]);
                if (r < rvj) vb = *reinterpret_cast<const float4*>(&Ab[(size_t)(c0 + r) * TT + k0 + c4]);
                At[c4 + 0][r] = va.x; At[c4 + 1][r] = va.y; At[c4 + 2][r] = va.z; At[c4 + 3][r] = va.w;
                Bs[c4 + 0][r] = vb.x; Bs[c4 + 1][r] = vb.y; Bs[c4 + 2][r] = vb.z; Bs[c4 + 3][r] = vb.w;
            }
            __syncthreads();
#pragma unroll 4
            for (int p = 0; p < 32; p++) {
                float4 a0 = *reinterpret_cast<const float4*>(&At[p][ty * 8]);
                float4 a1 = *reinterpret_cast<const float4*>(&At[p][ty * 8 + 4]);
                float4 b0 = *reinterpret_cast<const float4*>(&Bs[p][tx * 4]);
                float4 b1 = *reinterpret_cast<const float4*>(&Bs[p][tx * 4 + 64]);
                float aa[8] = {a0.x, a0.y, a0.z, a0.w, a1.x, a1.y, a1.z, a1.w};
                float bl[4] = {b0.x, b0.y, b0.z, b0.w};
                float bh[4] = {b1.x, b1.y, b1.z, b1.w};
                for (int i = 0; i < 8; i++) {
                    for (int j = 0; j < 4; j++) acc[i][j] += aa[i] * bl[j];
                    for (int j = 0; j < 4; j++) acc[i][j + 4] += aa[i] * bh[j];
                }
            }
        }
        if (tx * 4 >= rvj) return;
        for (int i = 0; i < 8; i++) {
            int rr = ty * 8 + i;
            if (rr >= rvi) break;
            // q==0 rows<64 cols<64 is diag(k+1): factor job owns that update
            if (!(q == 0 && rr < 64)) {
                float* cp0 = &Ab[(size_t)(r0 + rr) * TT + c0 + tx * 4];
                float4 cv0 = *reinterpret_cast<float4*>(cp0);
                cv0.x -= acc[i][0]; cv0.y -= acc[i][1]; cv0.z -= acc[i][2]; cv0.w -= acc[i][3];
                *reinterpret_cast<float4*>(cp0) = cv0;
            }
            if (rvj > 64) {
                float* cp1 = &Ab[(size_t)(r0 + rr) * TT + c0 + 64 + tx * 4];
                float4 cv1 = *reinterpret_cast<float4*>(cp1);
                cv1.x -= acc[i][4]; cv1.y -= acc[i][5]; cv1.z -= acc[i][6]; cv1.w -= acc[i][7];
                *reinterpret_cast<float4*>(cp1) = cv1;
            }
        }
        return;
    }
    if (q < TL + gz) {
        int e = q - TL;
        int ti = e / 9, sub = e % 9;
        int r0 = kb + 64 + ti * 128;
        int rvi = TT - r0; if (rvi > 128) rvi = 128;
        if (sub < 8) {
            int c0 = sub * 128;
            float acc[8][8] = {};
            for (int s = 0; s < 2; s++) {
                int k0 = kb + s * 32;
                __syncthreads();
                for (int l = 0; l < 4; l++) {
                    int f = l * 256 + t;
                    int r = f >> 3, c4 = (f & 7) * 4;
                    float4 va = make_float4(0.f, 0.f, 0.f, 0.f);
                    if (r < rvi) va = *reinterpret_cast<const float4*>(&Ab[(size_t)(r0 + r) * TT + k0 + c4]);
                    At[c4 + 0][r] = va.x; At[c4 + 1][r] = va.y; At[c4 + 2][r] = va.z; At[c4 + 3][r] = va.w;
                    int kr = f >> 5, cc4 = (f & 31) * 4;
                    float4 vb = *reinterpret_cast<const float4*>(&Gb[(size_t)(k0 + kr) * TT + c0 + cc4]);
                    *reinterpret_cast<float4*>(&Bs[kr][cc4]) = vb;
                }
                __syncthreads();
#pragma unroll 4
                for (int p = 0; p < 32; p++) {
                    float4 a0 = *reinterpret_cast<const float4*>(&At[p][ty * 8]);
                    float4 a1 = *reinterpret_cast<const float4*>(&At[p][ty * 8 + 4]);
                    float4 b0 = *reinterpret_cast<const float4*>(&Bs[p][tx * 4]);
                    float4 b1 = *reinterpret_cast<const float4*>(&Bs[p][tx * 4 + 64]);
                    float aa[8] = {a0.x, a0.y, a0.z, a0.w, a1.x, a1.y, a1.z, a1.w};
                    float bl[4] = {b0.x, b0.y, b0.z, b0.w};
                    float bh[4] = {b1.x, b1.y, b1.z, b1.w};
                    for (int i = 0; i < 8; i++) {
                        for (int j = 0; j < 4; j++) acc[i][j] += aa[i] * bl[j];
                        for (int j = 0; j < 4; j++) acc[i][j + 4] += aa[i] * bh[j];
                    }
                }
            }
            for (int i = 0; i < 8; i++) {
                int rr = ty * 8 + i;
                if (rr >= rvi) break;
                float* cp0 = &Gb[(size_t)(r0 + rr) * TT + c0 + tx * 4];
                float4 cv0 = *reinterpret_cast<float4*>(cp0);
                cv0.x -= acc[i][0]; cv0.y -= acc[i][1]; cv0.z -= acc[i][2]; cv0.w -= acc[i][3];
                *reinterpret_cast<float4*>(cp0) = cv0;
                float* cp1 = cp0 + 64;
                float4 cv1 = *reinterpret_cast<float4*>(cp1);
                cv1.x -= acc[i][4]; cv1.y -= acc[i][5]; cv1.z -= acc[i][6]; cv1.w -= acc[i][7];
                *reinterpret_cast<float4*>(cp1) = cv1;
            }
        } else {
            if (t < 64) zk[t] = zb[beta * TT + kb + t];
            float accz = 0.f;
            for (int s = 0; s < 2; s++) {
                int k0 = kb + s * 32;
                __syncthreads();
                for (int l = 0; l < 4; l++) {
                    int f = l * 256 + t;
                    int r = f >> 3, c4 = (f & 7) * 4;
                    float4 va = make_float4(0.f, 0.f, 0.f, 0.f);
                    if (r < rvi) va = *reinterpret_cast<const float4*>(&Ab[(size_t)(r0 + r) * TT + k0 + c4]);
                    At[c4 + 0][r] = va.x; At[c4 + 1][r] = va.y; At[c4 + 2][r] = va.z; At[c4 + 3][r] = va.w;
                }
                __syncthreads();
                if (t < 128) {
                    for (int qq = 0; qq < 32; qq++) accz += At[qq][t] * zk[s * 32 + qq];
                }
            }
            if (t < rvi) zb[beta * TT + r0 + t] -= accz;
        }
        return;
    }
    // ---- factor job: diag(k+1) = raw - P P^T, factor, -> Dfac[k+1] ----
    {
        int kb2 = kb + 64;
        for (int l = 0; l < 16; l++) {
            int e = l * 256 + t; int r = e >> 6, c = e & 63;
            FLd[r][c] = Ab[(size_t)(kb2 + r) * TT + kb2 + c];
            FPn[r][c] = Ab[(size_t)(kb2 + r) * TT + kb + c];
        }
        __syncthreads();
        {
            float acc[4][4] = {};
            for (int p = 0; p < 64; p++) {
                float a0 = FPn[ty * 4 + 0][p], a1 = FPn[ty * 4 + 1][p];
                float a2 = FPn[ty * 4 + 2][p], a3 = FPn[ty * 4 + 3][p];
                float b0 = FPn[tx * 4 + 0][p], b1 = FPn[tx * 4 + 1][p];
                float b2 = FPn[tx * 4 + 2][p], b3 = FPn[tx * 4 + 3][p];
                acc[0][0] += a0 * b0; acc[0][1] += a0 * b1; acc[0][2] += a0 * b2; acc[0][3] += a0 * b3;
                acc[1][0] += a1 * b0; acc[1][1] += a1 * b1; acc[1][2] += a1 * b2; acc[1][3] += a1 * b3;
                acc[2][0] += a2 * b0; acc[2][1] += a2 * b1; acc[2][2] += a2 * b2; acc[2][3] += a2 * b3;
                acc[3][0] += a3 * b0; acc[3][1] += a3 * b1; acc[3][2] += a3 * b2; acc[3][3] += a3 * b3;
            }
            for (int i = 0; i < 4; i++)
                for (int j = 0; j < 4; j++)
                    FLd[ty * 4 + i][tx * 4 + j] -= acc[i][j];
        }
        __syncthreads();
        for (int j = 0; j < 64; j++) {
            if (t == j) { float d = sqrtf(FLd[j][j]); FLd[j][j] = d; finv[j] = 1.0f / d; }
            __syncthreads();
            float lij = 0.f;
            if (t < 64 && t > j) { lij = FLd[t][j] * finv[j]; FLd[t][j] = lij; }
            __syncthreads();
            if (t < 64 && t > j) {
#pragma unroll 4
                for (int p = j + 1; p <= t; p++) FLd[t][p] -= lij * FLd[p][j];
            }
        }
        __syncthreads();
        float* DfO = Dfac + ((size_t)beta * 16 + (k + 1)) * 4096;
        for (int l = 0; l < 16; l++) {
            int e = l * 256 + t; int r = e >> 6, c = e & 63;
            DfO[r * 64 + c] = FLd[r][c];
        }
    }
}

// ---------------- cov = Kss - V^T V + JIT*I : 64x64 tiles + fused mean, XCD-pinned ----------------
__global__ __launch_bounds__(256) void k_cov64(const float* __restrict__ G,
                                               const float* __restrict__ xs,
                                               const int* __restrict__ ite,
                                               const float* __restrict__ lsp,
                                               const float* __restrict__ Bt,
                                               float* __restrict__ A,
                                               const float* __restrict__ zb,
                                               const float* __restrict__ mc,
                                               float* __restrict__ meanb,
                                               int b0, int bc) {
    int lin = blockIdx.x;
    int slot = lin & 7, tau = lin >> 3;
    int beta = ((slot - 4 * (tau & 1)) & 7) + (blockIdx.y << 3);
    if (beta >= bc) return;
    int ti, tj; tri_map(tau, ti, tj);
    int b = b0 + beta;
    const float* Gb = G + (size_t)beta * TT * TT;
    float* Ab = A + (size_t)beta * TT * TT;
    int i0 = ti * 64, j0 = tj * 64;
    __shared__ __align__(16) float Va[32][68];
    __shared__ __align__(16) float Vb[32][68];
    __shared__ float sxi[64], sxj[64], Btl[289], zs[32];
    __shared__ int sei[64], sej[64];
    int t = threadIdx.x, tx = t & 15, ty = t >> 4;
    if (t < 64) { sxi[t] = xs[b * TT + i0 + t]; sei[t] = ite[b * TT + i0 + t]; }
    else if (t < 128) { int u = t - 64; sxj[u] = xs[b * TT + j0 + u]; sej[u] = ite[b * TT + j0 + u]; }
    for (int e = t; e < 289; e += 256) Btl[e] = Bt[e];
    bool diag = (ti == tj);
    float acc[4][4] = {};
    float macc[4] = {0.f, 0.f, 0.f, 0.f};
    for (int k0 = 0; k0 < TT; k0 += 32) {
        __syncthreads();
        for (int l = 0; l < 2; l++) {
            int f = l * 256 + t;
            int kr = f >> 4, cc4 = (f & 15) * 4;
            *reinterpret_cast<float4*>(&Va[kr][cc4]) =
                *reinterpret_cast<const float4*>(&Gb[(size_t)(k0 + kr) * TT + i0 + cc4]);
            *reinterpret_cast<float4*>(&Vb[kr][cc4]) =
                *reinterpret_cast<const float4*>(&Gb[(size_t)(k0 + kr) * TT + j0 + cc4]);
        }
        if (diag && t < 32) zs[t] = zb[beta * TT + k0 + t];
        __syncthreads();
#pragma unroll 4
        for (int p = 0; p < 32; p++) {
            float4 av = *reinterpret_cast<const float4*>(&Va[p][ty * 4]);
            float4 bv = *reinterpret_cast<const float4*>(&Vb[p][tx * 4]);
            float aa[4] = {av.x, av.y, av.z, av.w};
            float bb[4] = {bv.x, bv.y, bv.z, bv.w};
            for (int i = 0; i < 4; i++)
                for (int j = 0; j < 4; j++) acc[i][j] += aa[i] * bb[j];
        }
        if (diag && ty == 0) {
#pragma unroll 4
            for (int p = 0; p < 32; p++) {
                float zv = zs[p];
                float4 av = *reinterpret_cast<const float4*>(&Va[p][tx * 4]);
                macc[0] += av.x * zv; macc[1] += av.y * zv;
                macc[2] += av.z * zv; macc[3] += av.w * zv;
            }
        }
    }
    float invls = 1.0f / lsp[0];
    for (int i = 0; i < 4; i++) {
        int ri = ty * 4 + i; int gi = i0 + ri;
        float xi = sxi[ri]; int ci = sei[ri] * 17;
        float vo[4];
        for (int j = 0; j < 4; j++) {
            int rj = tx * 4 + j; int gj = j0 + rj;
            float d = (xi - sxj[rj]) * invls;
            float v = expf(-0.5f * d * d) * Btl[ci + sej[rj]] - acc[i][j];
            if (gi == gj) v += JIT;
            vo[j] = v;
        }
        *reinterpret_cast<float4*>(&Ab[(size_t)gi * TT + j0 + tx * 4]) =
            make_float4(vo[0], vo[1], vo[2], vo[3]);
    }
    if (diag && ty == 0) {
        float c0 = mc[0];
        for (int j = 0; j < 4; j++)
            meanb[(size_t)b * TT + i0 + tx * 4 + j] = c0 + macc[j];
    }
}

// ---------------- P[c][j] = sum_{i>=j, ch(i)=c} Lstar[i][j] ----------------
__global__ __launch_bounds__(256) void k_P(const float* __restrict__ A,
                                           const int* __restrict__ ite,
                                           float* __restrict__ P, int b0) {
    int bz = blockIdx.y; int b = b0 + bz;
    const float* Ab = A + (size_t)bz * TT * TT;
    __shared__ int chl[TT];
    __shared__ float accl[CH * 256];
    int t = threadIdx.x;
    for (int i = t; i < TT; i += 256) chl[i] = ite[b * TT + i];
    for (int c = 0; c < CH; c++) accl[c * 256 + t] = 0.f;
    __syncthreads();
    int j0 = blockIdx.x * 256;
    int j = j0 + t;
    for (int i = j0; i < TT; i++) {
        float v = Ab[(size_t)i * TT + j];
        if (i >= j) accl[chl[i] * 256 + t] += v;
    }
    for (int c = 0; c < CH; c++) P[((size_t)b * CH + c) * TT + j] = accl[c * 256 + t];
}

// ---------------- msum[c] = sum_{ch(i)=c} mean[i] ----------------
__global__ __launch_bounds__(64) void k_msum(const float* __restrict__ meanb,
                                             const int* __restrict__ ite,
                                             float* __restrict__ msum, int b0) {
    int bz = blockIdx.x; int b = b0 + bz;
    __shared__ float pacc[CH][65];
    int t = threadIdx.x;
    for (int c = 0; c < CH; c++) pacc[c][t] = 0.f;
    __syncthreads();
    for (int i = t; i < TT; i += 64) pacc[ite[b * TT + i]][t] += meanb[b * TT + i];
    __syncthreads();
    if (t < CH) {
        float s = 0.f;
        for (int u = 0; u < 64; u++) s += pacc[t][u];
        msum[b * CH + t] = s;
    }
}

// ---------------- feat + classifier head ----------------
__global__ __launch_bounds__(256) void k_featout(const float* __restrict__ P,
                                                 const float* __restrict__ msum,
                                                 const float* __restrict__ eps,
                                                 const float* __restrict__ Wc,
                                                 const float* __restrict__ bc_,
                                                 float* __restrict__ out, int b0, int Btot) {
    int s = blockIdx.x; int b = b0 + blockIdx.y;
    __shared__ float el[TT];
    __shared__ float part[256];
    __shared__ float featl[CH];
    int t = threadIdx.x;
    for (int i = t; i < TT; i += 256) el[i] = eps[((size_t)s * Btot + b) * TT + i];
    __syncthreads();
    int c = t >> 4, seg = t & 15;
    float acc = 0.f;
    const float* Pr = &P[((size_t)b * CH + c) * TT + seg * 64];
    for (int j = 0; j < 64; j++) acc += Pr[j] * el[seg * 64 + j];
    part[t] = acc;
    __syncthreads();
    if (t < CH) {
        float s2 = msum[b * CH + t];
        for (int g = 0; g < 16; g++) s2 += part[t * 16 + g];
        featl[t] = s2 * (1.0f / 64.0f);
    }
    __syncthreads();
    if (t < NCLS) {
        float o = bc_[t];
        for (int c2 = 0; c2 < CH; c2++) o += featl[c2] * Wc[c2 * NCLS + t];
        out[((size_t)s * Btot + b) * NCLS + t] = o;
    }
}

extern "C" void kernel_launch(void* const* d_in, const int* in_sizes, int n_in,
                              void* d_out, int out_size, void* d_ws, size_t ws_size,
                              hipStream_t stream) {
    const float* inputs       = (const float*)d_in[0];
    const float* values       = (const float*)d_in[1];
    const float* test_inputs  = (const float*)d_in[2];
    const float* eps          = (const float*)d_in[3];
    const float* mc           = (const float*)d_in[4];
    const float* ls           = (const float*)d_in[5];
    const float* noise        = (const float*)d_in[6];
    const float* W_task       = (const float*)d_in[7];
    const float* v_task       = (const float*)d_in[8];
    const float* W_clf        = (const float*)d_in[9];
    const float* b_clf        = (const float*)d_in[10];
    const int*   indices      = (const int*)d_in[11];
    const int*   test_indices = (const int*)d_in[12];
    float* out = (float*)d_out;

    int Btot = in_sizes[1] / TT;   // 32

    float* ws = (float*)d_ws;
    size_t off = 0;
    float* Bt    = ws + off; off += 512;
    float* zbuf  = ws + off; off += (size_t)Btot * TT;
    float* meanb = ws + off; off += (size_t)Btot * TT;
    float* Pb    = ws + off; off += (size_t)Btot * CH * TT;
    float* msum  = ws + off; off += (size_t)Btot * CH;
    off = (off + 63) & ~(size_t)63;

    size_t avail = (ws_size / 4 > off) ? (ws_size / 4 - off) : 0;
    size_t per = 2 * (size_t)TT * TT + 16 * 4096;   // A + G + Dfac per batch
    int chunk = (int)(avail / per);
    if (chunk < 1) chunk = 1;
    if (chunk > Btot) chunk = Btot;
    float* bigA = ws + off;
    float* bigG = bigA + (size_t)chunk * TT * TT;
    float* Dfac = bigG + (size_t)chunk * TT * TT;

    k_btask<<<1, 256, 0, stream>>>(W_task, v_task, Bt);

    for (int b0 = 0; b0 < Btot; b0 += chunk) {
        int bcc = chunk; if (b0 + bcc > Btot) bcc = Btot - b0;
        int by = (bcc + 7) / 8;

        // ---- build Kxx, G, z; seed Dfac[0] ----
        k_build_kxx<<<dim3(8, 8, bcc), 256, 0, stream>>>(inputs, indices, ls, noise, Bt, bigA, b0);
        k_build_g<<<dim3(8, 8, bcc), 256, 0, stream>>>(test_inputs, inputs, test_indices, indices, ls, Bt, bigG, b0);
        k_zinit<<<bcc, 256, 0, stream>>>(values, mc, zbuf, b0);
        k_factor0<<<bcc, 256, 0, stream>>>(bigA, Dfac);
        // ---- merged chain: chol(Kxx) + V = L^{-1}G + z ----
        for (int k = 0; k < 16; k++) {
            int m = 15 - k;
            k_solveA<<<dim3(m + 9, bcc), 256, 0, stream>>>(bigA, bigG, zbuf, Dfac, k, m, 1);
            if (m > 0) {
                int nt = (64 * m + 127) / 128;
                int nq = nt * (nt + 1) / 2 + 9 * nt + 1;
                k_stepB64<<<dim3(nq * 8, by), 256, 0, stream>>>(bigA, bigG, zbuf, Dfac, k, m, bcc, 1);
            }
        }
        // ---- cov -> A (64x64 tiles) + fused mean; seed Dfac[0] ----
        k_cov64<<<dim3(136 * 8, by), 256, 0, stream>>>(bigG, test_inputs, test_indices, ls, Bt,
                                                       bigA, zbuf, mc, meanb, b0, bcc);
        k_factor0<<<bcc, 256, 0, stream>>>(bigA, Dfac);
        // ---- chol(cov) chain ----
        for (int k = 0; k < 16; k++) {
            int m = 15 - k;
            if (m > 0) {
                k_solveA<<<dim3(m, bcc), 256, 0, stream>>>(bigA, bigA, zbuf, Dfac, k, m, 0);
                int nt = (64 * m + 127) / 128;
                int nq = nt * (nt + 1) / 2 + 1;
                k_stepB64<<<dim3(nq * 8, by), 256, 0, stream>>>(bigA, bigA, zbuf, Dfac, k, m, bcc, 0);
            }
        }
        // ---- restore factored diag blocks for k_P ----
        k_diagfix64<<<dim3(16, bcc), 256, 0, stream>>>(bigA, Dfac);
        // ---- pooled sampling + classifier ----
        k_P<<<dim3(4, bcc), 256, 0, stream>>>(bigA, test_indices, Pb, b0);
        k_msum<<<bcc, 64, 0, stream>>>(meanb, test_indices, msum, b0);
        k_featout<<<dim3(SMC, bcc), 256, 0, stream>>>(Pb, msum, eps, W_clf, b_clf, out, b0, Btot);
    }
}

// Round 18
// 9070.120 us; speedup vs baseline: 1.6539x; 1.0573x over previous
//
#include <hip/hip_runtime.h>
#include <math.h>

#define TT 1024
#define CH 16
#define SMC 10
#define NCLS 10
#define JIT 1e-4f

__device__ __forceinline__ void tri_map(int tau, int& ti, int& tj) {
    int i = 0, r = tau;
    while (r >= i + 1) { r -= i + 1; i++; }
    ti = i; tj = r;
}

// ---------------- Btask = W W^T + diag(softplus(v)) ----------------
__global__ __launch_bounds__(256) void k_btask(const float* __restrict__ W,
                                               const float* __restrict__ v,
                                               float* __restrict__ Bt) {
    int t = threadIdx.x;
    for (int e = t; e < 17 * 17; e += 256) {
        int i = e / 17, j = e % 17;
        float s = 0.f;
        for (int r = 0; r < 3; r++) s += W[i * 3 + r] * W[j * 3 + r];
        if (i == j) s += log1pf(expf(v[i]));
        Bt[e] = s;
    }
}

// ---------------- Kxx build (lower 128-blocks) ----------------
__global__ __launch_bounds__(256) void k_build_kxx(const float* __restrict__ x,
                                                   const int* __restrict__ itr,
                                                   const float* __restrict__ lsp,
                                                   const float* __restrict__ noisep,
                                                   const float* __restrict__ Bt,
                                                   float* __restrict__ A, int b0) {
    int bi = blockIdx.x, bj = blockIdx.y, bz = blockIdx.z;
    if (bj > bi) return;
    int b = b0 + bz;
    __shared__ float sxi[128], sxj[128], Btl[289];
    __shared__ int sii[128], sij[128];
    int t = threadIdx.x;
    if (t < 128) { sxi[t] = x[b * TT + bi * 128 + t]; sii[t] = itr[b * TT + bi * 128 + t]; }
    else { int u = t - 128; sxj[u] = x[b * TT + bj * 128 + u]; sij[u] = itr[b * TT + bj * 128 + u]; }
    for (int e = t; e < 289; e += 256) Btl[e] = Bt[e];
    __syncthreads();
    float invls = 1.0f / lsp[0];
    float n2 = noisep[0] * noisep[0] + JIT;
    float* Ab = A + (size_t)bz * TT * TT;
    for (int l = 0; l < 64; l++) {
        int e = l * 256 + t;
        int r = e >> 7, c = e & 127;
        float d = (sxi[r] - sxj[c]) * invls;
        float kv = expf(-0.5f * d * d) * Btl[sii[r] * 17 + sij[c]];
        int gi = bi * 128 + r, gj = bj * 128 + c;
        if (gi == gj) kv += n2;
        Ab[(size_t)gi * TT + gj] = kv;
    }
}

// ---------------- G = Ksx^T build + fused z-init ----------------
__global__ __launch_bounds__(256) void k_build_g(const float* __restrict__ xs,
                                                 const float* __restrict__ x,
                                                 const int* __restrict__ ite,
                                                 const int* __restrict__ itr,
                                                 const float* __restrict__ lsp,
                                                 const float* __restrict__ Bt,
                                                 float* __restrict__ G,
                                                 const float* __restrict__ values,
                                                 const float* __restrict__ mc,
                                                 float* __restrict__ zb, int b0) {
    int bj = blockIdx.x, bi = blockIdx.y, bz = blockIdx.z;
    int b = b0 + bz;
    __shared__ float sxr[128], sxc[128], Btl[289];
    __shared__ int sir[128], sic[128];
    int t = threadIdx.x;
    if (t < 128) { sxr[t] = x[b * TT + bj * 128 + t]; sir[t] = itr[b * TT + bj * 128 + t]; }
    else { int u = t - 128; sxc[u] = xs[b * TT + bi * 128 + u]; sic[u] = ite[b * TT + bi * 128 + u]; }
    for (int e = t; e < 289; e += 256) Btl[e] = Bt[e];
    __syncthreads();
    float invls = 1.0f / lsp[0];
    float* Gb = G + (size_t)bz * TT * TT;
    for (int l = 0; l < 64; l++) {
        int e = l * 256 + t;
        int r = e >> 7, c = e & 127;
        float d = (sxc[c] - sxr[r]) * invls;
        float kv = expf(-0.5f * d * d) * Btl[sic[c] * 17 + sir[r]];
        Gb[(size_t)(bj * 128 + r) * TT + bi * 128 + c] = kv;
    }
    if (bi == 0 && bj == 0) {
        float c0 = mc[0];
        for (int i = t; i < TT; i += 256) zb[bz * TT + i] = values[(size_t)b * TT + i] - c0;
    }
}

// ---------------- seed: factor diag block 0 -> Dfac[0] ----------------
__global__ __launch_bounds__(256) void k_factor0(const float* __restrict__ A,
                                                 float* __restrict__ Dfac) {
    int bz = blockIdx.x;
    const float* Ab = A + (size_t)bz * TT * TT;
    __shared__ float Ld[64][65];
    __shared__ float invl[64];
    int t = threadIdx.x;
    for (int l = 0; l < 16; l++) {
        int e = l * 256 + t; int r = e >> 6, c = e & 63;
        Ld[r][c] = Ab[(size_t)r * TT + c];
    }
    __syncthreads();
    for (int j = 0; j < 64; j++) {
        if (t == j) { float d = sqrtf(Ld[j][j]); Ld[j][j] = d; invl[j] = 1.0f / d; }
        __syncthreads();
        float lij = 0.f;
        if (t < 64 && t > j) { lij = Ld[t][j] * invl[j]; Ld[t][j] = lij; }
        __syncthreads();
        if (t < 64 && t > j) {
#pragma unroll 4
            for (int p = j + 1; p <= t; p++) Ld[t][p] -= lij * Ld[p][j];
        }
    }
    __syncthreads();
    float* Df = Dfac + (size_t)bz * 16 * 4096;
    for (int l = 0; l < 16; l++) {
        int e = l * 256 + t; int r = e >> 6, c = e & 63;
        Df[r * 64 + c] = Ld[r][c];
    }
}

// ---------------- phase A: pure solves, diag loaded FACTORED from Dfac ----------------
__global__ __launch_bounds__(256) void k_solveA(float* __restrict__ A,
                                                float* __restrict__ G,
                                                float* __restrict__ zb,
                                                const float* __restrict__ Dfac,
                                                int k, int m, int withG) {
    int bx = blockIdx.x, bz = blockIdx.y;
    float* Ab = A + (size_t)bz * TT * TT;
    float* Gb = G + (size_t)bz * TT * TT;
    int kb = k * 64;
    __shared__ float Ld[64][65];
    __shared__ float WK[64][129];
    __shared__ float invl[64];
    __shared__ float zs[64];
    int t = threadIdx.x;
    const float* Df = Dfac + ((size_t)bz * 16 + k) * 4096;
    for (int l = 0; l < 16; l++) {
        int e = l * 256 + t; int r = e >> 6, c = e & 63;
        Ld[r][c] = Df[r * 64 + c];
    }
    int jtype, r0 = 0, c0 = 0;
    if (bx < m) {
        jtype = 1; r0 = kb + 64 * (bx + 1);
        for (int l = 0; l < 16; l++) {
            int e = l * 256 + t; int r = e >> 6, c = e & 63;
            WK[r][c] = Ab[(size_t)(r0 + r) * TT + kb + c];
        }
    } else if (withG && bx < m + 8) {
        jtype = 2; c0 = (bx - m) * 128;
        for (int l = 0; l < 32; l++) {
            int e = l * 256 + t; int r = e >> 7, c = e & 127;
            WK[r][c] = Gb[(size_t)(kb + r) * TT + c0 + c];
        }
    } else {
        jtype = 3;
        if (t < 64) zs[t] = zb[bz * TT + kb + t];
    }
    __syncthreads();
    if (t < 64) invl[t] = 1.0f / Ld[t][t];
    __syncthreads();
    if (jtype == 1) {
        if (t < 64) {
            for (int j = 0; j < 64; j++) {
                float xv = WK[t][j] * invl[j];
                WK[t][j] = xv;
#pragma unroll 4
                for (int p = j + 1; p < 64; p++) WK[t][p] -= Ld[p][j] * xv;
            }
        }
        __syncthreads();
        for (int l = 0; l < 16; l++) {
            int e = l * 256 + t; int r = e >> 6, c = e & 63;
            Ab[(size_t)(r0 + r) * TT + kb + c] = WK[r][c];
        }
    } else if (jtype == 2) {
        if (t < 128) {
            for (int j = 0; j < 64; j++) {
                float xv = WK[j][t] * invl[j];
                WK[j][t] = xv;
#pragma unroll 4
                for (int p = j + 1; p < 64; p++) WK[p][t] -= Ld[p][j] * xv;
            }
        }
        __syncthreads();
        for (int l = 0; l < 32; l++) {
            int e = l * 256 + t; int r = e >> 7, c = e & 127;
            Gb[(size_t)(kb + r) * TT + c0 + c] = WK[r][c];
        }
    } else {
        if (t == 0) {
            for (int j = 0; j < 64; j++) {
                float zv = zs[j] * invl[j];
                zs[j] = zv;
#pragma unroll 4
                for (int p = j + 1; p < 64; p++) zs[p] -= Ld[p][j] * zv;
            }
        }
        __syncthreads();
        if (t < 64) zb[bz * TT + kb + t] = zs[t];
    }
}

// ---------------- phase B: SYRK + G/z updates + NEXT-STEP diag factor, XCD-pinned ----------------
__global__ __launch_bounds__(256) void k_stepB64(float* __restrict__ A,
                                                 float* __restrict__ G,
                                                 float* __restrict__ zb,
                                                 float* __restrict__ Dfac,
                                                 int k, int m, int bc, int withG) {
    int lin = blockIdx.x;
    int slot = lin & 7, q = lin >> 3;
    int beta = ((slot - 4 * (q & 1)) & 7) + (blockIdx.y << 3);
    if (beta >= bc) return;
    float* Ab = A + (size_t)beta * TT * TT;
    float* Gb = G + (size_t)beta * TT * TT;
    int kb = k * 64;
    int nt = (64 * m + 127) / 128;
    int TL = nt * (nt + 1) / 2;
    int gz = withG ? 9 * nt : 0;
    __shared__ __align__(16) float sm[8448];
    float (*At)[132] = reinterpret_cast<float (*)[132]>(sm);
    float (*Bs)[132] = reinterpret_cast<float (*)[132]>(sm + 4224);
    float (*FLd)[65] = reinterpret_cast<float (*)[65]>(sm);
    float (*FPn)[65] = reinterpret_cast<float (*)[65]>(sm + 4160);
    __shared__ float zk[64];
    __shared__ float finv[64];
    int t = threadIdx.x, tx = t & 15, ty = t >> 4;
    if (q < TL) {
        int ti, tj; tri_map(q, ti, tj);
        int base = kb + 64;
        int r0 = base + ti * 128, c0 = base + tj * 128;
        int rvi = TT - r0; if (rvi > 128) rvi = 128;
        int rvj = TT - c0; if (rvj > 128) rvj = 128;
        float acc[8][8] = {};
        for (int s = 0; s < 2; s++) {
            int k0 = kb + s * 32;
            __syncthreads();
            for (int l = 0; l < 4; l++) {
                int f = l * 256 + t;
                int r = f >> 3, c4 = (f & 7) * 4;
                float4 va = make_float4(0.f, 0.f, 0.f, 0.f), vb = make_float4(0.f, 0.f, 0.f, 0.f);
                if (r < rvi) va = *reinterpret_cast<const float4*>(&Ab[(size_t)(r0 + r) * TT + k0 + c4]);
                if (r < rvj) vb = *reinterpret_cast<const float4*>(&Ab[(size_t)(c0 + r) * TT + k0 + c4]);
                At[c4 + 0][r] = va.x; At[c4 + 1][r] = va.y; At[c4 + 2][r] = va.z; At[c4 + 3][r] = va.w;
                Bs[c4 + 0][r] = vb.x; Bs[c4 + 1][r] = vb.y; Bs[c4 + 2][r] = vb.z; Bs[c4 + 3][r] = vb.w;
            }
            __syncthreads();
#pragma unroll 4
            for (int p = 0; p < 32; p++) {
                float4 a0 = *reinterpret_cast<const float4*>(&At[p][ty * 8]);
                float4 a1 = *reinterpret_cast<const float4*>(&At[p][ty * 8 + 4]);
                float4 b0 = *reinterpret_cast<const float4*>(&Bs[p][tx * 4]);
                float4 b1 = *reinterpret_cast<const float4*>(&Bs[p][tx * 4 + 64]);
                float aa[8] = {a0.x, a0.y, a0.z, a0.w, a1.x, a1.y, a1.z, a1.w};
                float bl[4] = {b0.x, b0.y, b0.z, b0.w};
                float bh[4] = {b1.x, b1.y, b1.z, b1.w};
                for (int i = 0; i < 8; i++) {
                    for (int j = 0; j < 4; j++) acc[i][j] += aa[i] * bl[j];
                    for (int j = 0; j < 4; j++) acc[i][j + 4] += aa[i] * bh[j];
                }
            }
        }
        if (tx * 4 >= rvj) return;
        for (int i = 0; i < 8; i++) {
            int rr = ty * 8 + i;
            if (rr >= rvi) break;
            if (!(q == 0 && rr < 64)) {
                float* cp0 = &Ab[(size_t)(r0 + rr) * TT + c0 + tx * 4];
                float4 cv0 = *reinterpret_cast<float4*>(cp0);
                cv0.x -= acc[i][0]; cv0.y -= acc[i][1]; cv0.z -= acc[i][2]; cv0.w -= acc[i][3];
                *reinterpret_cast<float4*>(cp0) = cv0;
            }
            if (rvj > 64) {
                float* cp1 = &Ab[(size_t)(r0 + rr) * TT + c0 + 64 + tx * 4];
                float4 cv1 = *reinterpret_cast<float4*>(cp1);
                cv1.x -= acc[i][4]; cv1.y -= acc[i][5]; cv1.z -= acc[i][6]; cv1.w -= acc[i][7];
                *reinterpret_cast<float4*>(cp1) = cv1;
            }
        }
        return;
    }
    if (q < TL + gz) {
        int e = q - TL;
        int ti = e / 9, sub = e % 9;
        int r0 = kb + 64 + ti * 128;
        int rvi = TT - r0; if (rvi > 128) rvi = 128;
        if (sub < 8) {
            int c0 = sub * 128;
            float acc[8][8] = {};
            for (int s = 0; s < 2; s++) {
                int k0 = kb + s * 32;
                __syncthreads();
                for (int l = 0; l < 4; l++) {
                    int f = l * 256 + t;
                    int r = f >> 3, c4 = (f & 7) * 4;
                    float4 va = make_float4(0.f, 0.f, 0.f, 0.f);
                    if (r < rvi) va = *reinterpret_cast<const float4*>(&Ab[(size_t)(r0 + r) * TT + k0 + c4]);
                    At[c4 + 0][r] = va.x; At[c4 + 1][r] = va.y; At[c4 + 2][r] = va.z; At[c4 + 3][r] = va.w;
                    int kr = f >> 5, cc4 = (f & 31) * 4;
                    float4 vb = *reinterpret_cast<const float4*>(&Gb[(size_t)(k0 + kr) * TT + c0 + cc4]);
                    *reinterpret_cast<float4*>(&Bs[kr][cc4]) = vb;
                }
                __syncthreads();
#pragma unroll 4
                for (int p = 0; p < 32; p++) {
                    float4 a0 = *reinterpret_cast<const float4*>(&At[p][ty * 8]);
                    float4 a1 = *reinterpret_cast<const float4*>(&At[p][ty * 8 + 4]);
                    float4 b0 = *reinterpret_cast<const float4*>(&Bs[p][tx * 4]);
                    float4 b1 = *reinterpret_cast<const float4*>(&Bs[p][tx * 4 + 64]);
                    float aa[8] = {a0.x, a0.y, a0.z, a0.w, a1.x, a1.y, a1.z, a1.w};
                    float bl[4] = {b0.x, b0.y, b0.z, b0.w};
                    float bh[4] = {b1.x, b1.y, b1.z, b1.w};
                    for (int i = 0; i < 8; i++) {
                        for (int j = 0; j < 4; j++) acc[i][j] += aa[i] * bl[j];
                        for (int j = 0; j < 4; j++) acc[i][j + 4] += aa[i] * bh[j];
                    }
                }
            }
            for (int i = 0; i < 8; i++) {
                int rr = ty * 8 + i;
                if (rr >= rvi) break;
                float* cp0 = &Gb[(size_t)(r0 + rr) * TT + c0 + tx * 4];
                float4 cv0 = *reinterpret_cast<float4*>(cp0);
                cv0.x -= acc[i][0]; cv0.y -= acc[i][1]; cv0.z -= acc[i][2]; cv0.w -= acc[i][3];
                *reinterpret_cast<float4*>(cp0) = cv0;
                float* cp1 = cp0 + 64;
                float4 cv1 = *reinterpret_cast<float4*>(cp1);
                cv1.x -= acc[i][4]; cv1.y -= acc[i][5]; cv1.z -= acc[i][6]; cv1.w -= acc[i][7];
                *reinterpret_cast<float4*>(cp1) = cv1;
            }
        } else {
            if (t < 64) zk[t] = zb[beta * TT + kb + t];
            float accz = 0.f;
            for (int s = 0; s < 2; s++) {
                int k0 = kb + s * 32;
                __syncthreads();
                for (int l = 0; l < 4; l++) {
                    int f = l * 256 + t;
                    int r = f >> 3, c4 = (f & 7) * 4;
                    float4 va = make_float4(0.f, 0.f, 0.f, 0.f);
                    if (r < rvi) va = *reinterpret_cast<const float4*>(&Ab[(size_t)(r0 + r) * TT + k0 + c4]);
                    At[c4 + 0][r] = va.x; At[c4 + 1][r] = va.y; At[c4 + 2][r] = va.z; At[c4 + 3][r] = va.w;
                }
                __syncthreads();
                if (t < 128) {
                    for (int qq = 0; qq < 32; qq++) accz += At[qq][t] * zk[s * 32 + qq];
                }
            }
            if (t < rvi) zb[beta * TT + r0 + t] -= accz;
        }
        return;
    }
    // ---- factor job: diag(k+1) = raw - P P^T, factor, -> Dfac[k+1] ----
    {
        int kb2 = kb + 64;
        for (int l = 0; l < 16; l++) {
            int e = l * 256 + t; int r = e >> 6, c = e & 63;
            FLd[r][c] = Ab[(size_t)(kb2 + r) * TT + kb2 + c];
            FPn[r][c] = Ab[(size_t)(kb2 + r) * TT + kb + c];
        }
        __syncthreads();
        {
            float acc[4][4] = {};
            for (int p = 0; p < 64; p++) {
                float a0 = FPn[ty * 4 + 0][p], a1 = FPn[ty * 4 + 1][p];
                float a2 = FPn[ty * 4 + 2][p], a3 = FPn[ty * 4 + 3][p];
                float b0 = FPn[tx * 4 + 0][p], b1 = FPn[tx * 4 + 1][p];
                float b2 = FPn[tx * 4 + 2][p], b3 = FPn[tx * 4 + 3][p];
                acc[0][0] += a0 * b0; acc[0][1] += a0 * b1; acc[0][2] += a0 * b2; acc[0][3] += a0 * b3;
                acc[1][0] += a1 * b0; acc[1][1] += a1 * b1; acc[1][2] += a1 * b2; acc[1][3] += a1 * b3;
                acc[2][0] += a2 * b0; acc[2][1] += a2 * b1; acc[2][2] += a2 * b2; acc[2][3] += a2 * b3;
                acc[3][0] += a3 * b0; acc[3][1] += a3 * b1; acc[3][2] += a3 * b2; acc[3][3] += a3 * b3;
            }
            for (int i = 0; i < 4; i++)
                for (int j = 0; j < 4; j++)
                    FLd[ty * 4 + i][tx * 4 + j] -= acc[i][j];
        }
        __syncthreads();
        for (int j = 0; j < 64; j++) {
            if (t == j) { float d = sqrtf(FLd[j][j]); FLd[j][j] = d; finv[j] = 1.0f / d; }
            __syncthreads();
            float lij = 0.f;
            if (t < 64 && t > j) { lij = FLd[t][j] * finv[j]; FLd[t][j] = lij; }
            __syncthreads();
            if (t < 64 && t > j) {
#pragma unroll 4
                for (int p = j + 1; p <= t; p++) FLd[t][p] -= lij * FLd[p][j];
            }
        }
        __syncthreads();
        float* DfO = Dfac + ((size_t)beta * 16 + (k + 1)) * 4096;
        for (int l = 0; l < 16; l++) {
            int e = l * 256 + t; int r = e >> 6, c = e & 63;
            DfO[r * 64 + c] = FLd[r][c];
        }
    }
}

// ---------------- cov = Kss - V^T V + JIT*I : 64x64 tiles + fused mean + P-zero ----------------
__global__ __launch_bounds__(256) void k_cov64(const float* __restrict__ G,
                                               const float* __restrict__ xs,
                                               const int* __restrict__ ite,
                                               const float* __restrict__ lsp,
                                               const float* __restrict__ Bt,
                                               float* __restrict__ A,
                                               const float* __restrict__ zb,
                                               const float* __restrict__ mc,
                                               float* __restrict__ meanb,
                                               float* __restrict__ P,
                                               int b0, int bc) {
    int lin = blockIdx.x;
    int slot = lin & 7, tau = lin >> 3;
    int beta = ((slot - 4 * (tau & 1)) & 7) + (blockIdx.y << 3);
    if (beta >= bc) return;
    int ti, tj; tri_map(tau, ti, tj);
    int b = b0 + beta;
    const float* Gb = G + (size_t)beta * TT * TT;
    float* Ab = A + (size_t)beta * TT * TT;
    int i0 = ti * 64, j0 = tj * 64;
    __shared__ __align__(16) float Va[32][68];
    __shared__ __align__(16) float Vb[32][68];
    __shared__ float sxi[64], sxj[64], Btl[289], zs[32];
    __shared__ int sei[64], sej[64];
    int t = threadIdx.x, tx = t & 15, ty = t >> 4;
    if (t < 64) { sxi[t] = xs[b * TT + i0 + t]; sei[t] = ite[b * TT + i0 + t]; }
    else if (t < 128) { int u = t - 64; sxj[u] = xs[b * TT + j0 + u]; sej[u] = ite[b * TT + j0 + u]; }
    for (int e = t; e < 289; e += 256) Btl[e] = Bt[e];
    bool diag = (ti == tj);
    float acc[4][4] = {};
    float macc[4] = {0.f, 0.f, 0.f, 0.f};
    for (int k0 = 0; k0 < TT; k0 += 32) {
        __syncthreads();
        for (int l = 0; l < 2; l++) {
            int f = l * 256 + t;
            int kr = f >> 4, cc4 = (f & 15) * 4;
            *reinterpret_cast<float4*>(&Va[kr][cc4]) =
                *reinterpret_cast<const float4*>(&Gb[(size_t)(k0 + kr) * TT + i0 + cc4]);
            *reinterpret_cast<float4*>(&Vb[kr][cc4]) =
                *reinterpret_cast<const float4*>(&Gb[(size_t)(k0 + kr) * TT + j0 + cc4]);
        }
        if (diag && t < 32) zs[t] = zb[beta * TT + k0 + t];
        __syncthreads();
#pragma unroll 4
        for (int p = 0; p < 32; p++) {
            float4 av = *reinterpret_cast<const float4*>(&Va[p][ty * 4]);
            float4 bv = *reinterpret_cast<const float4*>(&Vb[p][tx * 4]);
            float aa[4] = {av.x, av.y, av.z, av.w};
            float bb[4] = {bv.x, bv.y, bv.z, bv.w};
            for (int i = 0; i < 4; i++)
                for (int j = 0; j < 4; j++) acc[i][j] += aa[i] * bb[j];
        }
        if (diag && ty == 0) {
#pragma unroll 4
            for (int p = 0; p < 32; p++) {
                float zv = zs[p];
                float4 av = *reinterpret_cast<const float4*>(&Va[p][tx * 4]);
                macc[0] += av.x * zv; macc[1] += av.y * zv;
                macc[2] += av.z * zv; macc[3] += av.w * zv;
            }
        }
    }
    float invls = 1.0f / lsp[0];
    for (int i = 0; i < 4; i++) {
        int ri = ty * 4 + i; int gi = i0 + ri;
        float xi = sxi[ri]; int ci = sei[ri] * 17;
        float vo[4];
        for (int j = 0; j < 4; j++) {
            int rj = tx * 4 + j; int gj = j0 + rj;
            float d = (xi - sxj[rj]) * invls;
            float v = expf(-0.5f * d * d) * Btl[ci + sej[rj]] - acc[i][j];
            if (gi == gj) v += JIT;
            vo[j] = v;
        }
        *reinterpret_cast<float4*>(&Ab[(size_t)gi * TT + j0 + tx * 4]) =
            make_float4(vo[0], vo[1], vo[2], vo[3]);
    }
    if (diag) {
        if (ty == 0) {
            float c0 = mc[0];
            for (int j = 0; j < 4; j++)
                meanb[(size_t)b * TT + i0 + tx * 4 + j] = c0 + macc[j];
        }
        // zero P[b][*][i0..i0+63] for the upcoming atomic accumulation
        if (t < 64) {
            for (int c = 0; c < CH; c++)
                P[((size_t)b * CH + c) * TT + i0 + t] = 0.f;
        }
    }
}

// ---------------- P[c][j] += sum over 64-row segment (parallel, atomic) ----------------
// grid (4 jblocks, 16 row segments, bcc). Diag blocks read factored values from Dfac.
__global__ __launch_bounds__(256) void k_P(const float* __restrict__ A,
                                           const float* __restrict__ Dfac,
                                           const int* __restrict__ ite,
                                           float* __restrict__ P, int b0) {
    int jb = blockIdx.x, iseg = blockIdx.y, bz = blockIdx.z;
    int j = jb * 256 + threadIdx.x;
    if (iseg * 64 + 63 < jb * 256) return;   // entire segment above diagonal
    int b = b0 + bz;
    const float* Ab = A + (size_t)bz * TT * TT;
    const float* Df = Dfac + ((size_t)bz * 16 + iseg) * 4096;
    __shared__ int chl[64];
    __shared__ float accl[CH * 256];
    int t = threadIdx.x;
    if (t < 64) chl[t] = ite[b * TT + iseg * 64 + t];
    for (int c = 0; c < CH; c++) accl[c * 256 + t] = 0.f;
    __syncthreads();
    int jblk = j >> 6;
    for (int l = 0; l < 64; l++) {
        int i = iseg * 64 + l;
        if (i >= j) {
            float v = (jblk == iseg) ? Df[l * 64 + (j & 63)] : Ab[(size_t)i * TT + j];
            accl[chl[l] * 256 + t] += v;
        }
    }
    for (int c = 0; c < CH; c++) {
        float s = accl[c * 256 + t];
        if (s != 0.f) atomicAdd(&P[((size_t)b * CH + c) * TT + j], s);
    }
}

// ---------------- feat + classifier head (fused channel-sum of mean) ----------------
__global__ __launch_bounds__(256) void k_featout(const float* __restrict__ P,
                                                 const float* __restrict__ meanb,
                                                 const int* __restrict__ ite,
                                                 const float* __restrict__ eps,
                                                 const float* __restrict__ Wc,
                                                 const float* __restrict__ bc_,
                                                 float* __restrict__ out, int b0, int Btot) {
    int s = blockIdx.x; int b = b0 + blockIdx.y;
    __shared__ float el[TT];
    __shared__ float ml[TT];
    __shared__ int cl[TT];
    __shared__ float part[256];
    __shared__ float featl[CH];
    int t = threadIdx.x;
    for (int i = t; i < TT; i += 256) {
        el[i] = eps[((size_t)s * Btot + b) * TT + i];
        ml[i] = meanb[(size_t)b * TT + i];
        cl[i] = ite[(size_t)b * TT + i];
    }
    __syncthreads();
    int c = t >> 4, seg = t & 15;
    float acc = 0.f;
    const float* Pr = &P[((size_t)b * CH + c) * TT + seg * 64];
    for (int j = 0; j < 64; j++) {
        int idx = seg * 64 + j;
        acc += Pr[j] * el[idx];
        if (cl[idx] == c) acc += ml[idx];
    }
    part[t] = acc;
    __syncthreads();
    if (t < CH) {
        float s2 = 0.f;
        for (int g = 0; g < 16; g++) s2 += part[t * 16 + g];
        featl[t] = s2 * (1.0f / 64.0f);
    }
    __syncthreads();
    if (t < NCLS) {
        float o = bc_[t];
        for (int c2 = 0; c2 < CH; c2++) o += featl[c2] * Wc[c2 * NCLS + t];
        out[((size_t)s * Btot + b) * NCLS + t] = o;
    }
}

extern "C" void kernel_launch(void* const* d_in, const int* in_sizes, int n_in,
                              void* d_out, int out_size, void* d_ws, size_t ws_size,
                              hipStream_t stream) {
    const float* inputs       = (const float*)d_in[0];
    const float* values       = (const float*)d_in[1];
    const float* test_inputs  = (const float*)d_in[2];
    const float* eps          = (const float*)d_in[3];
    const float* mc           = (const float*)d_in[4];
    const float* ls           = (const float*)d_in[5];
    const float* noise        = (const float*)d_in[6];
    const float* W_task       = (const float*)d_in[7];
    const float* v_task       = (const float*)d_in[8];
    const float* W_clf        = (const float*)d_in[9];
    const float* b_clf        = (const float*)d_in[10];
    const int*   indices      = (const int*)d_in[11];
    const int*   test_indices = (const int*)d_in[12];
    float* out = (float*)d_out;

    int Btot = in_sizes[1] / TT;   // 32

    float* ws = (float*)d_ws;
    size_t off = 0;
    float* Bt    = ws + off; off += 512;
    float* zbuf  = ws + off; off += (size_t)Btot * TT;
    float* meanb = ws + off; off += (size_t)Btot * TT;
    float* Pb    = ws + off; off += (size_t)Btot * CH * TT;
    off = (off + 63) & ~(size_t)63;

    size_t avail = (ws_size / 4 > off) ? (ws_size / 4 - off) : 0;
    size_t per = 2 * (size_t)TT * TT + 16 * 4096;   // A + G + Dfac per batch
    int chunk = (int)(avail / per);
    if (chunk < 1) chunk = 1;
    if (chunk > Btot) chunk = Btot;
    float* bigA = ws + off;
    float* bigG = bigA + (size_t)chunk * TT * TT;
    float* Dfac = bigG + (size_t)chunk * TT * TT;

    k_btask<<<1, 256, 0, stream>>>(W_task, v_task, Bt);

    for (int b0 = 0; b0 < Btot; b0 += chunk) {
        int bcc = chunk; if (b0 + bcc > Btot) bcc = Btot - b0;
        int by = (bcc + 7) / 8;

        // ---- build Kxx, G (+z); seed Dfac[0] ----
        k_build_kxx<<<dim3(8, 8, bcc), 256, 0, stream>>>(inputs, indices, ls, noise, Bt, bigA, b0);
        k_build_g<<<dim3(8, 8, bcc), 256, 0, stream>>>(test_inputs, inputs, test_indices, indices,
                                                       ls, Bt, bigG, values, mc, zbuf, b0);
        k_factor0<<<bcc, 256, 0, stream>>>(bigA, Dfac);
        // ---- merged chain: chol(Kxx) + V = L^{-1}G + z ----
        for (int k = 0; k < 16; k++) {
            int m = 15 - k;
            k_solveA<<<dim3(m + 9, bcc), 256, 0, stream>>>(bigA, bigG, zbuf, Dfac, k, m, 1);
            if (m > 0) {
                int nt = (64 * m + 127) / 128;
                int nq = nt * (nt + 1) / 2 + 9 * nt + 1;
                k_stepB64<<<dim3(nq * 8, by), 256, 0, stream>>>(bigA, bigG, zbuf, Dfac, k, m, bcc, 1);
            }
        }
        // ---- cov -> A (64x64 tiles) + fused mean + P zero; seed Dfac[0] ----
        k_cov64<<<dim3(136 * 8, by), 256, 0, stream>>>(bigG, test_inputs, test_indices, ls, Bt,
                                                       bigA, zbuf, mc, meanb, Pb, b0, bcc);
        k_factor0<<<bcc, 256, 0, stream>>>(bigA, Dfac);
        // ---- chol(cov) chain ----
        for (int k = 0; k < 16; k++) {
            int m = 15 - k;
            if (m > 0) {
                k_solveA<<<dim3(m, bcc), 256, 0, stream>>>(bigA, bigA, zbuf, Dfac, k, m, 0);
                int nt = (64 * m + 127) / 128;
                int nq = nt * (nt + 1) / 2 + 1;
                k_stepB64<<<dim3(nq * 8, by), 256, 0, stream>>>(bigA, bigA, zbuf, Dfac, k, m, bcc, 0);
            }
        }
        // ---- pooled sampling + classifier ----
        k_P<<<dim3(4, 16, bcc), 256, 0, stream>>>(bigA, Dfac, test_indices, Pb, b0);
        k_featout<<<dim3(SMC, bcc), 256, 0, stream>>>(Pb, meanb, test_indices, eps, W_clf, b_clf, out, b0, Btot);
    }
}